// Round 11
// baseline (414.055 us; speedup 1.0000x reference)
//
#include <hip/hip_runtime.h>

// ---------- types / helpers ----------
typedef __attribute__((ext_vector_type(4))) float f32x4;
typedef __attribute__((ext_vector_type(8))) __bf16 bf16x8;

__device__ __forceinline__ unsigned short f2bf(float f) {
  unsigned int u = __builtin_bit_cast(unsigned int, f);
  return (unsigned short)((u + 0x7FFFu + ((u >> 16) & 1u)) >> 16);  // RNE
}

__device__ __forceinline__ float sin2pi(float x) {  // sin(2*pi*x)
#if __has_builtin(__builtin_amdgcn_sinf) && __has_builtin(__builtin_amdgcn_fractf)
  return __builtin_amdgcn_sinf(__builtin_amdgcn_fractf(x));
#else
  return __sinf(x * 6.283185307179586f);
#endif
}

__device__ __forceinline__ void gll16(const void* g, void* l) {
  __builtin_amdgcn_global_load_lds(
      (const __attribute__((address_space(1))) void*)g,
      (__attribute__((address_space(3))) void*)l, 16, 0, 0);
}

template <int W>
__device__ __forceinline__ void vmwait() {
  if constexpr (W == 0) asm volatile("s_waitcnt vmcnt(0)" ::: "memory");
  else if constexpr (W == 2) asm volatile("s_waitcnt vmcnt(2)" ::: "memory");
  else if constexpr (W == 4) asm volatile("s_waitcnt vmcnt(4)" ::: "memory");
  else if constexpr (W == 6) asm volatile("s_waitcnt vmcnt(6)" ::: "memory");
  else if constexpr (W == 8) asm volatile("s_waitcnt vmcnt(8)" ::: "memory");
}

// compile-time memory fence (no instruction): stops hipcc moving LDS/global ops
// across raw s_barrier (raw barrier builtin has NO memory semantics at IR level).
#define CFENCE() asm volatile("" ::: "memory")

// ---------- prep: per-(b,f) fourier data + effect_freq ----------
__global__ void prep_freq_k(const float* __restrict__ w, const float* __restrict__ affine_w,
                            const float* __restrict__ affine_b, const float* __restrict__ freqs,
                            const float* __restrict__ phases, float4* __restrict__ freq_data,
                            float* __restrict__ scal) {
  const int b = blockIdx.x, tid = threadIdx.x;
  const int wv = tid >> 6, lane = tid & 63;
  __shared__ float tdot[4];
  __shared__ float par[4];
  __shared__ float scnt;
  float sum = 0.f;
  for (int i = lane; i < 512; i += 64) sum += w[b * 512 + i] * affine_w[wv * 512 + i];
#pragma unroll
  for (int o = 32; o > 0; o >>= 1) sum += __shfl_down(sum, o);
  if (lane == 0) tdot[wv] = sum;
  if (tid == 0) scnt = 0.f;
  __syncthreads();
  if (tid == 0) {
    const float gain = 0.04419417382415922f;  // 1/sqrt(512)
    float t0 = tdot[0] * gain + affine_b[0];
    float t1 = tdot[1] * gain + affine_b[1];
    float t2 = tdot[2] * gain + affine_b[2];
    float t3 = tdot[3] * gain + affine_b[3];
    float inv = 1.f / sqrtf(t0 * t0 + t1 * t1);
    float c = t0 * inv, s = t1 * inv, tx = t2 * inv, ty = t3 * inv;
    par[0] = c; par[1] = s;
    par[2] = -c * tx + s * ty;   // shift0
    par[3] = -s * tx - c * ty;   // shift1
  }
  __syncthreads();
  const float c = par[0], s = par[1], sh0 = par[2], sh1 = par[3];
  float cnt = 0.f;
  for (int f = tid; f < 1024; f += 256) {
    float fx = freqs[2 * f], fy = freqs[2 * f + 1];
    float fb0 = fx * c + fy * s;
    float fb1 = fy * c - fx * s;
    float ph = phases[f] + fx * sh0 + fy * sh1;
    float nb = sqrtf(fb0 * fb0 + fb1 * fb1);
    float amp = fminf(fmaxf(1.f - (nb - 2.f) * (1.f / 30.f), 0.f), 1.f);
    float4 v; v.x = fb0; v.y = fb1; v.z = ph; v.w = amp;
    freq_data[(b << 10) + f] = v;
    if (sqrtf(fx * fx + fy * fy) < 2.f) cnt += 1.f;
  }
  if (b == 0) {
    atomicAdd(&scnt, cnt);   // integer-valued floats: exact, order-independent
    __syncthreads();
    if (tid == 0) scal[0] = 1.f / sqrtf(scnt);
  }
}

// ---------- prep: style s = fc(w, style_w, style_b); 4 lanes per output ----------
__global__ void style_k(const float* __restrict__ w, const float* __restrict__ style_w,
                        const float* __restrict__ style_b, float* __restrict__ s_out) {
  int gt = blockIdx.x * 256 + threadIdx.x;  // 32768 = 8192 outputs x 4 lanes
  int idx = gt >> 2, part = gt & 3;
  int b = idx >> 9, c = idx & 511;
  const float4* wr = (const float4*)(w + b * 512) + part * 32;
  const float4* sr = (const float4*)(style_w + (size_t)c * 512) + part * 32;
  float sum = 0.f;
#pragma unroll 4
  for (int i = 0; i < 32; ++i) {
    float4 a = wr[i], q = sr[i];
    sum += a.x * q.x + a.y * q.y + a.z * q.z + a.w * q.w;
  }
  sum += __shfl_xor(sum, 1);   // deterministic pairwise tree
  sum += __shfl_xor(sum, 2);
  if (part == 0) s_out[idx] = sum * 0.04419417382415922f + style_b[c];
}

// ---------- prep: conv weight normalize -> bt_conv (bf16 [o][kl*512+i]), wsumT[i][o] ----------
__global__ void convw_prep_k(const float* __restrict__ conv_w, float* __restrict__ wsumT,
                             unsigned short* __restrict__ bt_conv) {
  const int o = blockIdx.x, tid = threadIdx.x;
  __shared__ float red[256];
  float sum = 0.f;
  for (int i = tid; i < 4608; i += 256) { float v = conv_w[o * 4608 + i]; sum += v * v; }
  red[tid] = sum;
  __syncthreads();
  for (int off = 128; off > 0; off >>= 1) {
    if (tid < off) red[tid] += red[tid + off];
    __syncthreads();
  }
  const float rn = rsqrtf(red[0] * (1.f / 4608.f));
  for (int i = tid; i < 512; i += 256) {
    float sq = 0.f;
#pragma unroll
    for (int kl = 0; kl < 9; ++kl) {
      float v = conv_w[(o * 512 + i) * 9 + kl];
      sq += v * v;
      bt_conv[o * 4608 + kl * 512 + i] = f2bf(v * rn);
    }
    wsumT[i * 512 + o] = sq * rn * rn;  // transposed for coalesced dcoef reduce
  }
}

// ---------- prep: input_weight f32 -> bf16 ----------
__global__ void iw_cast_k(const float* __restrict__ iw, unsigned short* __restrict__ iw_bf) {
  int i = blockIdx.x * 256 + threadIdx.x;  // grid covers 524288 exactly
  iw_bf[i] = f2bf(iw[i]);
}

// ---------- prep: s_hat + dcoefs; 8 blocks per batch (o-range split) ----------
__global__ void shat_dcoef_k(const float* __restrict__ s, const float* __restrict__ wsumT,
                             float* __restrict__ s_hat, float* __restrict__ dcoefs) {
  const int b = blockIdx.x >> 3, og = blockIdx.x & 7, tid = threadIdx.x;
  __shared__ float red[256];
  __shared__ float sh2[512];
  __shared__ float red2[256];
  float sum = 0.f;
  for (int i = tid; i < 8192; i += 256) { float v = s[i]; sum += v * v; }
  red[tid] = sum;
  __syncthreads();
  for (int off = 128; off > 0; off >>= 1) {
    if (tid < off) red[tid] += red[tid + off];
    __syncthreads();
  }
  const float inv_rms = rsqrtf(red[0] * (1.f / 8192.f));
  for (int c = tid; c < 512; c += 256) {
    float sh = s[b * 512 + c] * inv_rms;
    if (og == 0) s_hat[b * 512 + c] = sh;
    sh2[c] = sh * sh;
  }
  __syncthreads();
  const int o = (og << 6) + (tid & 63);
  const int ic = tid >> 6;  // 0..3: i-chunk of 128
  float acc = 0.f;
  for (int i = ic * 128; i < ic * 128 + 128; ++i) acc += wsumT[i * 512 + o] * sh2[i];
  red2[tid] = acc;
  __syncthreads();
  if (tid < 64) {
    float a = red2[tid] + red2[tid + 64] + red2[tid + 128] + red2[tid + 192];
    dcoefs[b * 512 + o] = rsqrtf(a + 1e-8f);
  }
}

// ---------- border zero for padded xmp (replaces 71MB memset) ----------
__global__ void border_zero_k(unsigned short* __restrict__ xmp) {
  int idx = blockIdx.x * 256 + threadIdx.x;  // 16 b * 260 border px * 64 chunks = 266240
  int chunk = idx & 63;
  int t = idx >> 6;
  int p = t % 260;
  int b = t / 260;
  int h, w;
  if (p < 66) { h = 0; w = p; }
  else if (p < 132) { h = 65; w = p - 66; }
  else if (p < 196) { h = p - 131; w = 0; }
  else { h = p - 195; w = 65; }
  uint4 z; z.x = 0; z.y = 0; z.z = 0; z.w = 0;
  *(uint4*)&xmp[(((size_t)b * 66 + h) * 66 + w) * 512 + chunk * 8] = z;
}

// ---------- GEMM1 (R11): BN=512 -> sin computed ONCE per (pixel,freq) ----------
// M=65536, N=512 (one N-tile), K=1024, BK=64. 512 thr / 8 waves (2Mx4N), wave
// tile 64x128 (acc[4][8] unchanged -> bitwise-identical output). LDS: lA 16KB
// (swizzled sin tile) + lB dbuf 2x64KB = 144KB, 1 block/CU. Sync skeleton is
// the R8/R10-verified one: B staged 1-ahead into other buffer, lA rendezvous
// (lgkm0 + vmcnt(8) + barrier), fenced end-barrier. Per-thread staging is still
// 8 gll16 -> vmcnt(8) semantics identical to R10.
__device__ __forceinline__ void sy_sgB(char* lB, const unsigned short* iw, int d,
                                       int rb, int kt, int lane, int lsw) {
  const unsigned short* src = iw + (size_t)(rb + (lane >> 3)) * 1024 + (kt << 6) + lsw;
  gll16(src, lB + d * 65536 + rb * 128);
}

__global__ __launch_bounds__(512, 2) void synth_gemm4_k(
    const float4* __restrict__ freq_data, const unsigned short* __restrict__ iw_bf,
    const float* __restrict__ s_hat, const float* __restrict__ scal,
    unsigned short* __restrict__ xmp) {
  extern __shared__ char sl[];
  char* lA = sl;            // 128 rows x 128B, XOR-swizzled
  char* lB = sl + 16384;    // 2 x (512 rows x 128B), XOR-swizzled via source
  const int bid = blockIdx.x;
  const int wg = (bid & 7) * 64 + (bid >> 3);  // XCD swizzle (512 % 8 == 0)
  const int m0 = wg << 7;
  const int b = m0 >> 12;
  const int hbase = (m0 >> 6) & 63;
  const int tid = threadIdx.x, lane = tid & 63, wv = tid >> 6;
  const int wm = (wv >> 2) << 6;        // 2 M-halves of 64 rows
  const int wn = (wv & 3) << 7;         // 4 N-quarters of 128 cols
  const int g = tid & 31;               // freq pair (2 freqs of 64)
  const int r0 = (tid >> 5) << 3;       // 8 rows per thread (of 128)
  const int lsw = (((lane & 7) ^ (lane >> 3)) << 3);
  const int aswz = (((lane >> 4) << 4)) ^ ((lane & 7) << 4);
  const char* pA = lA + (size_t)(wm + (lane & 15)) * 128;
  const int browB = wn + (lane & 15);
  f32x4 acc[4][8];
#pragma unroll
  for (int mi = 0; mi < 4; ++mi)
#pragma unroll
    for (int ni = 0; ni < 8; ++ni) { f32x4 z = {0.f, 0.f, 0.f, 0.f}; acc[mi][ni] = z; }
  const float gy0 = (hbase + 0.5f) * 0.015625f - 0.5f;
  const float gy1 = (hbase + 1.5f) * 0.015625f - 0.5f;

  // prologue: stage B(0) into buf 0, drain, sync (wave wv stages rows wv*64..+63)
#pragma unroll
  for (int ig = 0; ig < 8; ++ig) sy_sgB(lB, iw_bf, 0, wv * 64 + ig * 8, 0, lane, lsw);
  vmwait<0>();
  __builtin_amdgcn_s_barrier();
  CFENCE();

  for (int kt = 0; kt < 16; ++kt) {
    // issue B(kt+1) first (flies under sin compute + MFMA)
    if (kt < 15) {
#pragma unroll
      for (int ig = 0; ig < 8; ++ig)
        sy_sgB(lB, iw_bf, (kt + 1) & 1, wv * 64 + ig * 8, kt + 1, lane, lsw);
    }
    // compute sin A-tile once (16 sins/thread; swizzled 4B writes, key (r&7)<<4)
    const float4* fdp = freq_data + (b << 10) + (kt << 6) + (g << 1);
    float4 fd0 = fdp[0], fd1 = fdp[1];
#pragma unroll
    for (int j = 0; j < 8; ++j) {
      const int r = r0 + j;
      const float gx = ((r & 63) + 0.5f) * 0.015625f - 0.5f;
      const float gy = (r >> 6) ? gy1 : gy0;
      ushort2 u;
      u.x = f2bf(sin2pi(gx * fd0.x + gy * fd0.y + fd0.z) * fd0.w);
      u.y = f2bf(sin2pi(gx * fd1.x + gy * fd1.y + fd1.z) * fd1.w);
      *(ushort2*)(lA + r * 128 + ((g << 2) ^ ((r & 7) << 4))) = u;
    }
    // own A ds_writes drained, own share of B(kt) landed, then all-wave rendezvous.
    asm volatile("s_waitcnt lgkmcnt(0)" ::: "memory");
    if (kt < 15) vmwait<8>(); else vmwait<0>();
    __builtin_amdgcn_s_barrier();
    CFENCE();                               // reads below must not hoist above barrier
    __builtin_amdgcn_sched_barrier(0);

    const char* pB = lB + ((kt & 1) << 16) + (size_t)browB * 128;
#pragma unroll
    for (int ks = 0; ks < 2; ++ks) {
      const int ao = aswz ^ (ks << 6);
      bf16x8 af[4], bq[8];
#pragma unroll
      for (int mi = 0; mi < 4; ++mi) af[mi] = *(const bf16x8*)(pA + mi * 2048 + ao);
#pragma unroll
      for (int ni = 0; ni < 8; ++ni) bq[ni] = *(const bf16x8*)(pB + ni * 2048 + ao);
      __builtin_amdgcn_s_setprio(1);
#pragma unroll
      for (int mi = 0; mi < 4; ++mi)
#pragma unroll
        for (int ni = 0; ni < 8; ++ni)
          acc[mi][ni] = __builtin_amdgcn_mfma_f32_16x16x32_bf16(af[mi], bq[ni], acc[mi][ni], 0, 0, 0);
      __builtin_amdgcn_s_setprio(0);
    }
    CFENCE();                               // reads above stay above barrier
    __builtin_amdgcn_s_barrier();           // protect lA/lB rewrite next kt
    CFENCE();                               // next-iter stores stay below barrier
  }

  const float inv_eff = scal[0];
  const int c_lo = lane & 15, r_hi = (lane >> 4) << 2;
#pragma unroll
  for (int ni = 0; ni < 8; ++ni) {
    const int cc = wn + (ni << 4) + c_lo;
    const float sc = s_hat[b * 512 + cc] * inv_eff;
#pragma unroll
    for (int mi = 0; mi < 4; ++mi) {
#pragma unroll
      for (int j = 0; j < 4; ++j) {
        const int rr = wm + (mi << 4) + r_hi + j;
        const int hp = hbase + (rr >> 6) + 1;
        const int wp = (rr & 63) + 1;
        xmp[(((size_t)b * 66 + hp) * 66 + wp) * 512 + cc] = f2bf(acc[mi][ni][j] * sc);
      }
    }
  }
}

__device__ __forceinline__ float epi_act(float a, float dco, float cb) {
  float y = a * dco + cb;
  y = (y >= 0.f ? y : 0.2f * y) * 1.4142135623730951f;
  return fminf(fmaxf(y, -256.f), 256.f);
}

// ---------- GEMM2: 3x3 conv, 256x256 tile, BK=64, 8 waves (R8-verified) ----------
// kc-major tile order; single-barrier K-tile; all staging 1 tile ahead into D^1.
struct ConvCtx {
  const unsigned short* xmp;
  const unsigned short* bt;
  int n0, hb, b_img, lane;
  int lsw;
  int gB_rb0;
  int gA_lo;
  int gA_up;
};

__device__ __forceinline__ void tile_geom(int t, int& dh, int& dw, int& kc, int& koff) {
  const int kc8 = t / 9;
  const int off = t - 9 * kc8;
  dh = off / 3;
  dw = off - 3 * dh;
  kc = kc8 << 6;
  koff = off * 512 + kc;
}

__device__ __forceinline__ void sgA(char* lds, const ConvCtx& c, int d, int rb,
                                    int dh, int dw, int kc) {
  const int r = rb + (c.lane >> 3);
  const int h = c.hb + (r >> 6) + dh;
  const int w = (r & 63) + dw;
  const unsigned short* src = c.xmp + (((size_t)c.b_img * 66 + h) * 66 + w) * 512 + kc + c.lsw;
  gll16(src, lds + d * 32768 + rb * 128);
}

__device__ __forceinline__ void sgB(char* lds, const ConvCtx& c, int d, int rb, int koff) {
  const int row = c.n0 + rb + (c.lane >> 3);
  const unsigned short* src = c.bt + (size_t)row * 4608 + koff + c.lsw;
  gll16(src, lds + 65536 + d * 32768 + rb * 128);
}

template <bool STG>
__device__ __forceinline__ void conv_tile1(char* lds, const ConvCtx& c, f32x4 (&acc)[8][4],
                                           const char* pA, const char* pB, int aswz0, int t) {
  int dh1, dw1, kc1, koff1;
  tile_geom(t + 1, dh1, dw1, kc1, koff1);
  const int D = t & 1, Dn = D ^ 1;
  const int db = D << 15;
  const int a0 = aswz0, a1 = aswz0 ^ 64;

  vmwait<0>();                       // all stages for tile t (issued during t-1) landed
  __builtin_amdgcn_s_barrier();      // + every wave's stages landed, t-1 reads done
  CFENCE();
  __builtin_amdgcn_sched_barrier(0);

  bf16x8 bq[4], af[4];
  // ---- ks0, mh0 | issue B(t+1) -> D^1 ----
#pragma unroll
  for (int ni = 0; ni < 4; ++ni) bq[ni] = *(const bf16x8*)(pB + db + ni * 2048 + a0);
#pragma unroll
  for (int i = 0; i < 4; ++i) af[i] = *(const bf16x8*)(pA + db + i * 2048 + a0);
  if (STG) {
    sgB(lds, c, Dn, c.gB_rb0, koff1);      sgB(lds, c, Dn, c.gB_rb0 + 8, koff1);
    sgB(lds, c, Dn, c.gB_rb0 + 16, koff1); sgB(lds, c, Dn, c.gB_rb0 + 24, koff1);
  }
  __builtin_amdgcn_s_setprio(1);
#pragma unroll
  for (int i = 0; i < 4; ++i)
#pragma unroll
    for (int ni = 0; ni < 4; ++ni)
      acc[i][ni] = __builtin_amdgcn_mfma_f32_16x16x32_bf16(af[i], bq[ni], acc[i][ni], 0, 0, 0);
  __builtin_amdgcn_s_setprio(0);
  // ---- ks0, mh1 | issue A-up(t+1), A-lo(t+1) -> D^1 ----
#pragma unroll
  for (int i = 0; i < 4; ++i) af[i] = *(const bf16x8*)(pA + db + (4 + i) * 2048 + a0);
  if (STG) {
    sgA(lds, c, Dn, c.gA_up, dh1, dw1, kc1); sgA(lds, c, Dn, c.gA_up + 8, dh1, dw1, kc1);
    sgA(lds, c, Dn, c.gA_lo, dh1, dw1, kc1); sgA(lds, c, Dn, c.gA_lo + 8, dh1, dw1, kc1);
  }
  __builtin_amdgcn_s_setprio(1);
#pragma unroll
  for (int i = 0; i < 4; ++i)
#pragma unroll
    for (int ni = 0; ni < 4; ++ni)
      acc[4 + i][ni] = __builtin_amdgcn_mfma_f32_16x16x32_bf16(af[i], bq[ni], acc[4 + i][ni], 0, 0, 0);
  __builtin_amdgcn_s_setprio(0);
  // ---- ks1, mh0 ----
#pragma unroll
  for (int ni = 0; ni < 4; ++ni) bq[ni] = *(const bf16x8*)(pB + db + ni * 2048 + a1);
#pragma unroll
  for (int i = 0; i < 4; ++i) af[i] = *(const bf16x8*)(pA + db + i * 2048 + a1);
  __builtin_amdgcn_s_setprio(1);
#pragma unroll
  for (int i = 0; i < 4; ++i)
#pragma unroll
    for (int ni = 0; ni < 4; ++ni)
      acc[i][ni] = __builtin_amdgcn_mfma_f32_16x16x32_bf16(af[i], bq[ni], acc[i][ni], 0, 0, 0);
  __builtin_amdgcn_s_setprio(0);
  // ---- ks1, mh1 ----
#pragma unroll
  for (int i = 0; i < 4; ++i) af[i] = *(const bf16x8*)(pA + db + (4 + i) * 2048 + a1);
  __builtin_amdgcn_s_setprio(1);
#pragma unroll
  for (int i = 0; i < 4; ++i)
#pragma unroll
    for (int ni = 0; ni < 4; ++ni)
      acc[4 + i][ni] = __builtin_amdgcn_mfma_f32_16x16x32_bf16(af[i], bq[ni], acc[4 + i][ni], 0, 0, 0);
  __builtin_amdgcn_s_setprio(0);
  CFENCE();
}

__global__ __launch_bounds__(512, 2) void conv_gemm8_k(
    const unsigned short* __restrict__ xmp, const unsigned short* __restrict__ bt_conv,
    const float* __restrict__ dcoefs, const float* __restrict__ conv_b,
    float* __restrict__ out) {
  extern __shared__ char lds[];
  const int tid = threadIdx.x, lane = tid & 63, wv = tid >> 6;
  const int bid = blockIdx.x;
  const int wg = (bid & 7) * 64 + (bid >> 3);  // XCD-bijective swizzle (512 % 8 == 0)
  const int mt = wg >> 1, nt = wg & 1;
  const int m0 = mt << 8, n0 = nt << 8;
  const int b_img = m0 >> 12;
  const int hb = (m0 >> 6) & 63;
  const int wm = (wv >> 2) << 7, wn = (wv & 3) << 6;

  ConvCtx c;
  c.xmp = xmp; c.bt = bt_conv;
  c.n0 = n0; c.hb = hb; c.b_img = b_img; c.lane = lane;
  c.lsw = (((lane & 7) ^ (lane >> 3)) << 3);
  c.gB_rb0 = (((wv & 3) >> 1) << 7) + (((wv & 1) | ((wv >> 2) << 1)) << 5);
  c.gA_lo = wm + ((wv & 3) << 4);
  c.gA_up = c.gA_lo + 64;

  const char* pA = lds + (size_t)(wm + (lane & 15)) * 128;
  const char* pB = lds + 65536 + (size_t)(wn + (lane & 15)) * 128;
  const int aswz0 = (((lane >> 4) << 4)) ^ ((lane & 7) << 4);

  f32x4 acc[8][4];
#pragma unroll
  for (int mi = 0; mi < 8; ++mi)
#pragma unroll
    for (int ni = 0; ni < 4; ++ni) { f32x4 z = {0.f, 0.f, 0.f, 0.f}; acc[mi][ni] = z; }

  // Prologue: stage tile 0 (kc=0, off=0) fully into buf 0. Waited by tile 0's vmcnt(0).
  sgB(lds, c, 0, c.gB_rb0, 0);       sgB(lds, c, 0, c.gB_rb0 + 8, 0);
  sgB(lds, c, 0, c.gB_rb0 + 16, 0);  sgB(lds, c, 0, c.gB_rb0 + 24, 0);
  sgA(lds, c, 0, c.gA_up, 0, 0, 0);  sgA(lds, c, 0, c.gA_up + 8, 0, 0, 0);
  sgA(lds, c, 0, c.gA_lo, 0, 0, 0);  sgA(lds, c, 0, c.gA_lo + 8, 0, 0, 0);

  // 72 K-tiles, kc-major; one barrier + one vmcnt(0) per tile.
  for (int t = 0; t < 71; ++t) conv_tile1<true>(lds, c, acc, pA, pB, aswz0, t);
  conv_tile1<false>(lds, c, acc, pA, pB, aswz0, 71);

  // Epilogue
  const int c_lo = lane & 15, r_hi = (lane >> 4) << 2;
#pragma unroll
  for (int ni = 0; ni < 4; ++ni) {
    const int oo = n0 + wn + (ni << 4) + c_lo;
    const float dco = dcoefs[b_img * 512 + oo];
    const float cb = conv_b[oo];
#pragma unroll
    for (int mi = 0; mi < 8; ++mi) {
      const int rr = wm + (mi << 4) + r_hi;
      const int hh = hb + (rr >> 6);
      const int w0 = rr & 63;
      float4 v;
      v.x = epi_act(acc[mi][ni][0], dco, cb);
      v.y = epi_act(acc[mi][ni][1], dco, cb);
      v.z = epi_act(acc[mi][ni][2], dco, cb);
      v.w = epi_act(acc[mi][ni][3], dco, cb);
      *(float4*)&out[(((size_t)b_img * 512 + oo) * 64 + hh) * 64 + w0] = v;
    }
  }
}

// ---------- launch ----------
extern "C" void kernel_launch(void* const* d_in, const int* in_sizes, int n_in,
                              void* d_out, int out_size, void* d_ws, size_t ws_size,
                              hipStream_t stream) {
  (void)in_sizes; (void)n_in; (void)out_size;
  const float* w        = (const float*)d_in[0];
  const float* affine_w = (const float*)d_in[1];
  const float* affine_b = (const float*)d_in[2];
  const float* freqs    = (const float*)d_in[3];
  const float* phases   = (const float*)d_in[4];
  const float* input_weight = (const float*)d_in[5];
  const float* style_w  = (const float*)d_in[6];
  const float* style_b  = (const float*)d_in[7];
  const float* conv_w   = (const float*)d_in[8];
  const float* conv_b   = (const float*)d_in[9];
  float* out = (float*)d_out;

  char* p = (char*)d_ws;
  float4* freq_data = (float4*)p;               p += (size_t)16 * 1024 * 16;
  float* scal = (float*)p;                      p += 256;
  float* s_buf = (float*)p;                     p += 8192 * 4;
  float* s_hat = (float*)p;                     p += 8192 * 4;
  float* wsumT = (float*)p;                     p += (size_t)512 * 512 * 4;
  float* dcoefs = (float*)p;                    p += 8192 * 4;
  unsigned short* iw_bf = (unsigned short*)p;   p += (size_t)512 * 1024 * 2;
  unsigned short* bt_conv = (unsigned short*)p; p += (size_t)512 * 4608 * 2;
  unsigned short* xmp = (unsigned short*)p;     p += (size_t)16 * 66 * 66 * 512 * 2;
  if (ws_size < (size_t)(p - (char*)d_ws)) return;  // workspace too small: fail loudly

  (void)hipFuncSetAttribute((const void*)conv_gemm8_k,
                            hipFuncAttributeMaxDynamicSharedMemorySize, 131072);
  (void)hipFuncSetAttribute((const void*)synth_gemm4_k,
                            hipFuncAttributeMaxDynamicSharedMemorySize, 147456);

  border_zero_k<<<1040, 256, 0, stream>>>(xmp);
  prep_freq_k<<<16, 256, 0, stream>>>(w, affine_w, affine_b, freqs, phases, freq_data, scal);
  style_k<<<128, 256, 0, stream>>>(w, style_w, style_b, s_buf);
  convw_prep_k<<<512, 256, 0, stream>>>(conv_w, wsumT, bt_conv);
  iw_cast_k<<<2048, 256, 0, stream>>>(input_weight, iw_bf);
  shat_dcoef_k<<<128, 256, 0, stream>>>(s_buf, wsumT, s_hat, dcoefs);
  synth_gemm4_k<<<512, 512, 147456, stream>>>(freq_data, iw_bf, s_hat, scal, xmp);
  conv_gemm8_k<<<512, 512, 131072, stream>>>(xmp, bt_conv, dcoefs, conv_b, out);
}

// Round 12
// 392.797 us; speedup vs baseline: 1.0541x; 1.0541x over previous
//
#include <hip/hip_runtime.h>

// ---------- types / helpers ----------
typedef __attribute__((ext_vector_type(4))) float f32x4;
typedef __attribute__((ext_vector_type(8))) __bf16 bf16x8;

__device__ __forceinline__ unsigned short f2bf(float f) {
  unsigned int u = __builtin_bit_cast(unsigned int, f);
  return (unsigned short)((u + 0x7FFFu + ((u >> 16) & 1u)) >> 16);  // RNE
}

__device__ __forceinline__ float sin2pi(float x) {  // sin(2*pi*x)
#if __has_builtin(__builtin_amdgcn_sinf) && __has_builtin(__builtin_amdgcn_fractf)
  return __builtin_amdgcn_sinf(__builtin_amdgcn_fractf(x));
#else
  return __sinf(x * 6.283185307179586f);
#endif
}

__device__ __forceinline__ void gll16(const void* g, void* l) {
  __builtin_amdgcn_global_load_lds(
      (const __attribute__((address_space(1))) void*)g,
      (__attribute__((address_space(3))) void*)l, 16, 0, 0);
}

template <int W>
__device__ __forceinline__ void vmwait() {
  if constexpr (W == 0) asm volatile("s_waitcnt vmcnt(0)" ::: "memory");
  else if constexpr (W == 2) asm volatile("s_waitcnt vmcnt(2)" ::: "memory");
  else if constexpr (W == 4) asm volatile("s_waitcnt vmcnt(4)" ::: "memory");
  else if constexpr (W == 6) asm volatile("s_waitcnt vmcnt(6)" ::: "memory");
  else if constexpr (W == 8) asm volatile("s_waitcnt vmcnt(8)" ::: "memory");
}

// compile-time memory fence (no instruction): stops hipcc moving LDS/global ops
// across raw s_barrier (raw barrier builtin has NO memory semantics at IR level).
#define CFENCE() asm volatile("" ::: "memory")

// ---------- fused independent preps (border / prep_freq / style / convw / iw_cast) ----------
// All blocks 256 threads; branches are block-uniform so per-branch __syncthreads is safe.
__global__ void fused_prep_k(const float* __restrict__ w, const float* __restrict__ affine_w,
                             const float* __restrict__ affine_b, const float* __restrict__ freqs,
                             const float* __restrict__ phases, const float* __restrict__ style_w,
                             const float* __restrict__ style_b, const float* __restrict__ conv_w,
                             const float* __restrict__ iw,
                             float4* __restrict__ freq_data, float* __restrict__ scal,
                             float* __restrict__ s_out, float* __restrict__ wsumT,
                             unsigned short* __restrict__ bt_conv,
                             unsigned short* __restrict__ iw_bf,
                             unsigned short* __restrict__ xmp) {
  const int bid = blockIdx.x, tid = threadIdx.x;
  if (bid < 1040) {
    // ---- border zero for padded xmp (16 b * 260 border px * 64 chunks = 266240) ----
    int idx = bid * 256 + tid;
    int chunk = idx & 63;
    int t = idx >> 6;
    int p = t % 260;
    int b = t / 260;
    int h, wq;
    if (p < 66) { h = 0; wq = p; }
    else if (p < 132) { h = 65; wq = p - 66; }
    else if (p < 196) { h = p - 131; wq = 0; }
    else { h = p - 195; wq = 65; }
    uint4 z; z.x = 0; z.y = 0; z.z = 0; z.w = 0;
    *(uint4*)&xmp[(((size_t)b * 66 + h) * 66 + wq) * 512 + chunk * 8] = z;
  } else if (bid < 1056) {
    // ---- prep_freq: per-(b,f) fourier data + effect_freq ----
    const int b = bid - 1040;
    const int wv = tid >> 6, lane = tid & 63;
    __shared__ float tdot[4];
    __shared__ float par[4];
    __shared__ float scnt;
    float sum = 0.f;
    for (int i = lane; i < 512; i += 64) sum += w[b * 512 + i] * affine_w[wv * 512 + i];
#pragma unroll
    for (int o = 32; o > 0; o >>= 1) sum += __shfl_down(sum, o);
    if (lane == 0) tdot[wv] = sum;
    if (tid == 0) scnt = 0.f;
    __syncthreads();
    if (tid == 0) {
      const float gain = 0.04419417382415922f;  // 1/sqrt(512)
      float t0 = tdot[0] * gain + affine_b[0];
      float t1 = tdot[1] * gain + affine_b[1];
      float t2 = tdot[2] * gain + affine_b[2];
      float t3 = tdot[3] * gain + affine_b[3];
      float inv = 1.f / sqrtf(t0 * t0 + t1 * t1);
      float c = t0 * inv, s = t1 * inv, tx = t2 * inv, ty = t3 * inv;
      par[0] = c; par[1] = s;
      par[2] = -c * tx + s * ty;   // shift0
      par[3] = -s * tx - c * ty;   // shift1
    }
    __syncthreads();
    const float c = par[0], s = par[1], sh0 = par[2], sh1 = par[3];
    float cnt = 0.f;
    for (int f = tid; f < 1024; f += 256) {
      float fx = freqs[2 * f], fy = freqs[2 * f + 1];
      float fb0 = fx * c + fy * s;
      float fb1 = fy * c - fx * s;
      float ph = phases[f] + fx * sh0 + fy * sh1;
      float nb = sqrtf(fb0 * fb0 + fb1 * fb1);
      float amp = fminf(fmaxf(1.f - (nb - 2.f) * (1.f / 30.f), 0.f), 1.f);
      float4 v; v.x = fb0; v.y = fb1; v.z = ph; v.w = amp;
      freq_data[(b << 10) + f] = v;
      if (sqrtf(fx * fx + fy * fy) < 2.f) cnt += 1.f;
    }
    if (b == 0) {
      atomicAdd(&scnt, cnt);   // integer-valued floats: exact, order-independent
      __syncthreads();
      if (tid == 0) scal[0] = 1.f / sqrtf(scnt);
    }
  } else if (bid < 1184) {
    // ---- style: s = fc(w, style_w, style_b); 4 lanes per output ----
    int gt = (bid - 1056) * 256 + tid;  // 32768 = 8192 outputs x 4 lanes
    int idx = gt >> 2, part = gt & 3;
    int b = idx >> 9, c = idx & 511;
    const float4* wr = (const float4*)(w + b * 512) + part * 32;
    const float4* sr = (const float4*)(style_w + (size_t)c * 512) + part * 32;
    float sum = 0.f;
#pragma unroll 4
    for (int i = 0; i < 32; ++i) {
      float4 a = wr[i], q = sr[i];
      sum += a.x * q.x + a.y * q.y + a.z * q.z + a.w * q.w;
    }
    sum += __shfl_xor(sum, 1);   // deterministic pairwise tree
    sum += __shfl_xor(sum, 2);
    if (part == 0) s_out[idx] = sum * 0.04419417382415922f + style_b[c];
  } else if (bid < 1696) {
    // ---- convw: normalize -> bt_conv (bf16 [o][kl*512+i]), wsumT[i][o] ----
    const int o = bid - 1184;
    __shared__ float red[256];
    float sum = 0.f;
    for (int i = tid; i < 4608; i += 256) { float v = conv_w[o * 4608 + i]; sum += v * v; }
    red[tid] = sum;
    __syncthreads();
    for (int off = 128; off > 0; off >>= 1) {
      if (tid < off) red[tid] += red[tid + off];
      __syncthreads();
    }
    const float rn = rsqrtf(red[0] * (1.f / 4608.f));
    for (int i = tid; i < 512; i += 256) {
      float sq = 0.f;
#pragma unroll
      for (int kl = 0; kl < 9; ++kl) {
        float v = conv_w[(o * 512 + i) * 9 + kl];
        sq += v * v;
        bt_conv[o * 4608 + kl * 512 + i] = f2bf(v * rn);
      }
      wsumT[i * 512 + o] = sq * rn * rn;  // transposed for coalesced dcoef reduce
    }
  } else {
    // ---- iw_cast: input_weight f32 -> bf16 (covers 524288 exactly) ----
    int i = (bid - 1696) * 256 + tid;
    iw_bf[i] = f2bf(iw[i]);
  }
}

// ---------- prep: s_hat + dcoefs; 8 blocks per batch (o-range split) ----------
__global__ void shat_dcoef_k(const float* __restrict__ s, const float* __restrict__ wsumT,
                             float* __restrict__ s_hat, float* __restrict__ dcoefs) {
  const int b = blockIdx.x >> 3, og = blockIdx.x & 7, tid = threadIdx.x;
  __shared__ float red[256];
  __shared__ float sh2[512];
  __shared__ float red2[256];
  float sum = 0.f;
  for (int i = tid; i < 8192; i += 256) { float v = s[i]; sum += v * v; }
  red[tid] = sum;
  __syncthreads();
  for (int off = 128; off > 0; off >>= 1) {
    if (tid < off) red[tid] += red[tid + off];
    __syncthreads();
  }
  const float inv_rms = rsqrtf(red[0] * (1.f / 8192.f));
  for (int c = tid; c < 512; c += 256) {
    float sh = s[b * 512 + c] * inv_rms;
    if (og == 0) s_hat[b * 512 + c] = sh;
    sh2[c] = sh * sh;
  }
  __syncthreads();
  const int o = (og << 6) + (tid & 63);
  const int ic = tid >> 6;  // 0..3: i-chunk of 128
  float acc = 0.f;
  for (int i = ic * 128; i < ic * 128 + 128; ++i) acc += wsumT[i * 512 + o] * sh2[i];
  red2[tid] = acc;
  __syncthreads();
  if (tid < 64) {
    float a = red2[tid] + red2[tid + 64] + red2[tid + 128] + red2[tid + 192];
    dcoefs[b * 512 + o] = rsqrtf(a + 1e-8f);
  }
}

// ---------- GEMM1 (R12): BN=512, sin once; NEW coalesced LDS-transpose epilogue ----------
// M=65536, N=512, K=1024, BK=64. 512 thr / 8 waves (2Mx4N), wave tile 64x128.
// LDS: lA 16KB (swizzled sin) + lB dbuf 2x64KB = 144KB (1 block/CU). K-loop sync
// skeleton is R8/R10/R11-verified. Epilogue: stage scaled bf16 into LDS
// [128 rows][520 ch] (1040B row stride: 16B-aligned, 2-way-bank-free), barrier,
// then 16x {ds_read_b128 + 1KB-contiguous global_store_dwordx4 per wave}.
__device__ __forceinline__ void sy_sgB(char* lB, const unsigned short* iw, int d,
                                       int rb, int kt, int lane, int lsw) {
  const unsigned short* src = iw + (size_t)(rb + (lane >> 3)) * 1024 + (kt << 6) + lsw;
  gll16(src, lB + d * 65536 + rb * 128);
}

__global__ __launch_bounds__(512, 2) void synth_gemm4_k(
    const float4* __restrict__ freq_data, const unsigned short* __restrict__ iw_bf,
    const float* __restrict__ s_hat, const float* __restrict__ scal,
    unsigned short* __restrict__ xmp) {
  extern __shared__ char sl[];
  char* lA = sl;            // 128 rows x 128B, XOR-swizzled
  char* lB = sl + 16384;    // 2 x (512 rows x 128B), XOR-swizzled via source
  const int bid = blockIdx.x;
  const int wg = (bid & 7) * 64 + (bid >> 3);  // XCD swizzle (512 % 8 == 0)
  const int m0 = wg << 7;
  const int b = m0 >> 12;
  const int hbase = (m0 >> 6) & 63;
  const int tid = threadIdx.x, lane = tid & 63, wv = tid >> 6;
  const int wm = (wv >> 2) << 6;        // 2 M-halves of 64 rows
  const int wn = (wv & 3) << 7;         // 4 N-quarters of 128 cols
  const int g = tid & 31;               // freq pair (2 freqs of 64)
  const int r0 = (tid >> 5) << 3;       // 8 rows per thread (of 128)
  const int lsw = (((lane & 7) ^ (lane >> 3)) << 3);
  const int aswz = (((lane >> 4) << 4)) ^ ((lane & 7) << 4);
  const char* pA = lA + (size_t)(wm + (lane & 15)) * 128;
  const int browB = wn + (lane & 15);
  f32x4 acc[4][8];
#pragma unroll
  for (int mi = 0; mi < 4; ++mi)
#pragma unroll
    for (int ni = 0; ni < 8; ++ni) { f32x4 z = {0.f, 0.f, 0.f, 0.f}; acc[mi][ni] = z; }
  const float gy0 = (hbase + 0.5f) * 0.015625f - 0.5f;
  const float gy1 = (hbase + 1.5f) * 0.015625f - 0.5f;

  // prologue: stage B(0) into buf 0, drain, sync (wave wv stages rows wv*64..+63)
#pragma unroll
  for (int ig = 0; ig < 8; ++ig) sy_sgB(lB, iw_bf, 0, wv * 64 + ig * 8, 0, lane, lsw);
  vmwait<0>();
  __builtin_amdgcn_s_barrier();
  CFENCE();

  for (int kt = 0; kt < 16; ++kt) {
    // issue B(kt+1) first (flies under sin compute + MFMA)
    if (kt < 15) {
#pragma unroll
      for (int ig = 0; ig < 8; ++ig)
        sy_sgB(lB, iw_bf, (kt + 1) & 1, wv * 64 + ig * 8, kt + 1, lane, lsw);
    }
    // compute sin A-tile once (16 sins/thread; swizzled 4B writes, key (r&7)<<4)
    const float4* fdp = freq_data + (b << 10) + (kt << 6) + (g << 1);
    float4 fd0 = fdp[0], fd1 = fdp[1];
#pragma unroll
    for (int j = 0; j < 8; ++j) {
      const int r = r0 + j;
      const float gx = ((r & 63) + 0.5f) * 0.015625f - 0.5f;
      const float gy = (r >> 6) ? gy1 : gy0;
      ushort2 u;
      u.x = f2bf(sin2pi(gx * fd0.x + gy * fd0.y + fd0.z) * fd0.w);
      u.y = f2bf(sin2pi(gx * fd1.x + gy * fd1.y + fd1.z) * fd1.w);
      *(ushort2*)(lA + r * 128 + ((g << 2) ^ ((r & 7) << 4))) = u;
    }
    // own A ds_writes drained, own share of B(kt) landed, then all-wave rendezvous.
    asm volatile("s_waitcnt lgkmcnt(0)" ::: "memory");
    if (kt < 15) vmwait<8>(); else vmwait<0>();
    __builtin_amdgcn_s_barrier();
    CFENCE();                               // reads below must not hoist above barrier
    __builtin_amdgcn_sched_barrier(0);

    const char* pB = lB + ((kt & 1) << 16) + (size_t)browB * 128;
#pragma unroll
    for (int ks = 0; ks < 2; ++ks) {
      const int ao = aswz ^ (ks << 6);
      bf16x8 af[4], bq[8];
#pragma unroll
      for (int mi = 0; mi < 4; ++mi) af[mi] = *(const bf16x8*)(pA + mi * 2048 + ao);
#pragma unroll
      for (int ni = 0; ni < 8; ++ni) bq[ni] = *(const bf16x8*)(pB + ni * 2048 + ao);
      __builtin_amdgcn_s_setprio(1);
#pragma unroll
      for (int mi = 0; mi < 4; ++mi)
#pragma unroll
        for (int ni = 0; ni < 8; ++ni)
          acc[mi][ni] = __builtin_amdgcn_mfma_f32_16x16x32_bf16(af[mi], bq[ni], acc[mi][ni], 0, 0, 0);
      __builtin_amdgcn_s_setprio(0);
    }
    CFENCE();                               // reads above stay above barrier
    __builtin_amdgcn_s_barrier();           // protect lA/lB rewrite next kt
    CFENCE();                               // next-iter stores stay below barrier
  }
  // K-loop's final barrier: every wave is done reading lA/lB -> reuse LDS below.

  // ---- epilogue: LDS transpose (row stride 520 ch = 1040B) -> coalesced stores ----
  const float inv_eff = scal[0];
  const int c_lo = lane & 15, r_hi = (lane >> 4) << 2;
  unsigned short* lT = (unsigned short*)sl;   // 128 x 520 x 2B = 133120 <= 147456
#pragma unroll
  for (int ni = 0; ni < 8; ++ni) {
    const int cc = wn + (ni << 4) + c_lo;
    const float sc = s_hat[b * 512 + cc] * inv_eff;
#pragma unroll
    for (int mi = 0; mi < 4; ++mi) {
#pragma unroll
      for (int j = 0; j < 4; ++j) {
        const int rr = wm + (mi << 4) + r_hi + j;
        lT[rr * 520 + cc] = f2bf(acc[mi][ni][j] * sc);
      }
    }
  }
  asm volatile("s_waitcnt lgkmcnt(0)" ::: "memory");  // own lT writes drained
  __builtin_amdgcn_s_barrier();                       // all waves' lT complete
  CFENCE();
#pragma unroll
  for (int it = 0; it < 16; ++it) {
    const int chunk = it * 512 + tid;   // 8192 chunks x 16B = 128 rows x 1KB
    const int row = chunk >> 6;
    const int co = (chunk & 63) << 3;   // 8 channels per 16B
    uint4 v = *(const uint4*)&lT[row * 520 + co];
    const int hp = hbase + (row >> 6) + 1;
    const int wp = (row & 63) + 1;
    *(uint4*)&xmp[(((size_t)b * 66 + hp) * 66 + wp) * 512 + co] = v;
  }
}

__device__ __forceinline__ float epi_act(float a, float dco, float cb) {
  float y = a * dco + cb;
  y = (y >= 0.f ? y : 0.2f * y) * 1.4142135623730951f;
  return fminf(fmaxf(y, -256.f), 256.f);
}

// ---------- GEMM2: 3x3 conv, 256x256 tile, BK=64, 8 waves (R8-verified) ----------
// kc-major tile order; single-barrier K-tile; all staging 1 tile ahead into D^1.
struct ConvCtx {
  const unsigned short* xmp;
  const unsigned short* bt;
  int n0, hb, b_img, lane;
  int lsw;
  int gB_rb0;
  int gA_lo;
  int gA_up;
};

__device__ __forceinline__ void tile_geom(int t, int& dh, int& dw, int& kc, int& koff) {
  const int kc8 = t / 9;
  const int off = t - 9 * kc8;
  dh = off / 3;
  dw = off - 3 * dh;
  kc = kc8 << 6;
  koff = off * 512 + kc;
}

__device__ __forceinline__ void sgA(char* lds, const ConvCtx& c, int d, int rb,
                                    int dh, int dw, int kc) {
  const int r = rb + (c.lane >> 3);
  const int h = c.hb + (r >> 6) + dh;
  const int w = (r & 63) + dw;
  const unsigned short* src = c.xmp + (((size_t)c.b_img * 66 + h) * 66 + w) * 512 + kc + c.lsw;
  gll16(src, lds + d * 32768 + rb * 128);
}

__device__ __forceinline__ void sgB(char* lds, const ConvCtx& c, int d, int rb, int koff) {
  const int row = c.n0 + rb + (c.lane >> 3);
  const unsigned short* src = c.bt + (size_t)row * 4608 + koff + c.lsw;
  gll16(src, lds + 65536 + d * 32768 + rb * 128);
}

template <bool STG>
__device__ __forceinline__ void conv_tile1(char* lds, const ConvCtx& c, f32x4 (&acc)[8][4],
                                           const char* pA, const char* pB, int aswz0, int t) {
  int dh1, dw1, kc1, koff1;
  tile_geom(t + 1, dh1, dw1, kc1, koff1);
  const int D = t & 1, Dn = D ^ 1;
  const int db = D << 15;
  const int a0 = aswz0, a1 = aswz0 ^ 64;

  vmwait<0>();                       // all stages for tile t (issued during t-1) landed
  __builtin_amdgcn_s_barrier();      // + every wave's stages landed, t-1 reads done
  CFENCE();
  __builtin_amdgcn_sched_barrier(0);

  bf16x8 bq[4], af[4];
  // ---- ks0, mh0 | issue B(t+1) -> D^1 ----
#pragma unroll
  for (int ni = 0; ni < 4; ++ni) bq[ni] = *(const bf16x8*)(pB + db + ni * 2048 + a0);
#pragma unroll
  for (int i = 0; i < 4; ++i) af[i] = *(const bf16x8*)(pA + db + i * 2048 + a0);
  if (STG) {
    sgB(lds, c, Dn, c.gB_rb0, koff1);      sgB(lds, c, Dn, c.gB_rb0 + 8, koff1);
    sgB(lds, c, Dn, c.gB_rb0 + 16, koff1); sgB(lds, c, Dn, c.gB_rb0 + 24, koff1);
  }
  __builtin_amdgcn_s_setprio(1);
#pragma unroll
  for (int i = 0; i < 4; ++i)
#pragma unroll
    for (int ni = 0; ni < 4; ++ni)
      acc[i][ni] = __builtin_amdgcn_mfma_f32_16x16x32_bf16(af[i], bq[ni], acc[i][ni], 0, 0, 0);
  __builtin_amdgcn_s_setprio(0);
  // ---- ks0, mh1 | issue A-up(t+1), A-lo(t+1) -> D^1 ----
#pragma unroll
  for (int i = 0; i < 4; ++i) af[i] = *(const bf16x8*)(pA + db + (4 + i) * 2048 + a0);
  if (STG) {
    sgA(lds, c, Dn, c.gA_up, dh1, dw1, kc1); sgA(lds, c, Dn, c.gA_up + 8, dh1, dw1, kc1);
    sgA(lds, c, Dn, c.gA_lo, dh1, dw1, kc1); sgA(lds, c, Dn, c.gA_lo + 8, dh1, dw1, kc1);
  }
  __builtin_amdgcn_s_setprio(1);
#pragma unroll
  for (int i = 0; i < 4; ++i)
#pragma unroll
    for (int ni = 0; ni < 4; ++ni)
      acc[4 + i][ni] = __builtin_amdgcn_mfma_f32_16x16x32_bf16(af[i], bq[ni], acc[4 + i][ni], 0, 0, 0);
  __builtin_amdgcn_s_setprio(0);
  // ---- ks1, mh0 ----
#pragma unroll
  for (int ni = 0; ni < 4; ++ni) bq[ni] = *(const bf16x8*)(pB + db + ni * 2048 + a1);
#pragma unroll
  for (int i = 0; i < 4; ++i) af[i] = *(const bf16x8*)(pA + db + i * 2048 + a1);
  __builtin_amdgcn_s_setprio(1);
#pragma unroll
  for (int i = 0; i < 4; ++i)
#pragma unroll
    for (int ni = 0; ni < 4; ++ni)
      acc[i][ni] = __builtin_amdgcn_mfma_f32_16x16x32_bf16(af[i], bq[ni], acc[i][ni], 0, 0, 0);
  __builtin_amdgcn_s_setprio(0);
  // ---- ks1, mh1 ----
#pragma unroll
  for (int i = 0; i < 4; ++i) af[i] = *(const bf16x8*)(pA + db + (4 + i) * 2048 + a1);
  __builtin_amdgcn_s_setprio(1);
#pragma unroll
  for (int i = 0; i < 4; ++i)
#pragma unroll
    for (int ni = 0; ni < 4; ++ni)
      acc[4 + i][ni] = __builtin_amdgcn_mfma_f32_16x16x32_bf16(af[i], bq[ni], acc[4 + i][ni], 0, 0, 0);
  __builtin_amdgcn_s_setprio(0);
  CFENCE();
}

__global__ __launch_bounds__(512, 2) void conv_gemm8_k(
    const unsigned short* __restrict__ xmp, const unsigned short* __restrict__ bt_conv,
    const float* __restrict__ dcoefs, const float* __restrict__ conv_b,
    float* __restrict__ out) {
  extern __shared__ char lds[];
  const int tid = threadIdx.x, lane = tid & 63, wv = tid >> 6;
  const int bid = blockIdx.x;
  const int wg = (bid & 7) * 64 + (bid >> 3);  // XCD-bijective swizzle (512 % 8 == 0)
  const int mt = wg >> 1, nt = wg & 1;
  const int m0 = mt << 8, n0 = nt << 8;
  const int b_img = m0 >> 12;
  const int hb = (m0 >> 6) & 63;
  const int wm = (wv >> 2) << 7, wn = (wv & 3) << 6;

  ConvCtx c;
  c.xmp = xmp; c.bt = bt_conv;
  c.n0 = n0; c.hb = hb; c.b_img = b_img; c.lane = lane;
  c.lsw = (((lane & 7) ^ (lane >> 3)) << 3);
  c.gB_rb0 = (((wv & 3) >> 1) << 7) + (((wv & 1) | ((wv >> 2) << 1)) << 5);
  c.gA_lo = wm + ((wv & 3) << 4);
  c.gA_up = c.gA_lo + 64;

  const char* pA = lds + (size_t)(wm + (lane & 15)) * 128;
  const char* pB = lds + 65536 + (size_t)(wn + (lane & 15)) * 128;
  const int aswz0 = (((lane >> 4) << 4)) ^ ((lane & 7) << 4);

  f32x4 acc[8][4];
#pragma unroll
  for (int mi = 0; mi < 8; ++mi)
#pragma unroll
    for (int ni = 0; ni < 4; ++ni) { f32x4 z = {0.f, 0.f, 0.f, 0.f}; acc[mi][ni] = z; }

  // Prologue: stage tile 0 (kc=0, off=0) fully into buf 0. Waited by tile 0's vmcnt(0).
  sgB(lds, c, 0, c.gB_rb0, 0);       sgB(lds, c, 0, c.gB_rb0 + 8, 0);
  sgB(lds, c, 0, c.gB_rb0 + 16, 0);  sgB(lds, c, 0, c.gB_rb0 + 24, 0);
  sgA(lds, c, 0, c.gA_up, 0, 0, 0);  sgA(lds, c, 0, c.gA_up + 8, 0, 0, 0);
  sgA(lds, c, 0, c.gA_lo, 0, 0, 0);  sgA(lds, c, 0, c.gA_lo + 8, 0, 0, 0);

  // 72 K-tiles, kc-major; one barrier + one vmcnt(0) per tile.
  for (int t = 0; t < 71; ++t) conv_tile1<true>(lds, c, acc, pA, pB, aswz0, t);
  conv_tile1<false>(lds, c, acc, pA, pB, aswz0, 71);

  // Epilogue
  const int c_lo = lane & 15, r_hi = (lane >> 4) << 2;
#pragma unroll
  for (int ni = 0; ni < 4; ++ni) {
    const int oo = n0 + wn + (ni << 4) + c_lo;
    const float dco = dcoefs[b_img * 512 + oo];
    const float cb = conv_b[oo];
#pragma unroll
    for (int mi = 0; mi < 8; ++mi) {
      const int rr = wm + (mi << 4) + r_hi;
      const int hh = hb + (rr >> 6);
      const int w0 = rr & 63;
      float4 v;
      v.x = epi_act(acc[mi][ni][0], dco, cb);
      v.y = epi_act(acc[mi][ni][1], dco, cb);
      v.z = epi_act(acc[mi][ni][2], dco, cb);
      v.w = epi_act(acc[mi][ni][3], dco, cb);
      *(float4*)&out[(((size_t)b_img * 512 + oo) * 64 + hh) * 64 + w0] = v;
    }
  }
}

// ---------- launch ----------
extern "C" void kernel_launch(void* const* d_in, const int* in_sizes, int n_in,
                              void* d_out, int out_size, void* d_ws, size_t ws_size,
                              hipStream_t stream) {
  (void)in_sizes; (void)n_in; (void)out_size;
  const float* w        = (const float*)d_in[0];
  const float* affine_w = (const float*)d_in[1];
  const float* affine_b = (const float*)d_in[2];
  const float* freqs    = (const float*)d_in[3];
  const float* phases   = (const float*)d_in[4];
  const float* input_weight = (const float*)d_in[5];
  const float* style_w  = (const float*)d_in[6];
  const float* style_b  = (const float*)d_in[7];
  const float* conv_w   = (const float*)d_in[8];
  const float* conv_b   = (const float*)d_in[9];
  float* out = (float*)d_out;

  char* p = (char*)d_ws;
  float4* freq_data = (float4*)p;               p += (size_t)16 * 1024 * 16;
  float* scal = (float*)p;                      p += 256;
  float* s_buf = (float*)p;                     p += 8192 * 4;
  float* s_hat = (float*)p;                     p += 8192 * 4;
  float* wsumT = (float*)p;                     p += (size_t)512 * 512 * 4;
  float* dcoefs = (float*)p;                    p += 8192 * 4;
  unsigned short* iw_bf = (unsigned short*)p;   p += (size_t)512 * 1024 * 2;
  unsigned short* bt_conv = (unsigned short*)p; p += (size_t)512 * 4608 * 2;
  unsigned short* xmp = (unsigned short*)p;     p += (size_t)16 * 66 * 66 * 512 * 2;
  if (ws_size < (size_t)(p - (char*)d_ws)) return;  // workspace too small: fail loudly

  (void)hipFuncSetAttribute((const void*)conv_gemm8_k,
                            hipFuncAttributeMaxDynamicSharedMemorySize, 131072);
  (void)hipFuncSetAttribute((const void*)synth_gemm4_k,
                            hipFuncAttributeMaxDynamicSharedMemorySize, 147456);

  fused_prep_k<<<3744, 256, 0, stream>>>(w, affine_w, affine_b, freqs, phases,
                                         style_w, style_b, conv_w, input_weight,
                                         freq_data, scal, s_buf, wsumT, bt_conv,
                                         iw_bf, xmp);
  shat_dcoef_k<<<128, 256, 0, stream>>>(s_buf, wsumT, s_hat, dcoefs);
  synth_gemm4_k<<<512, 512, 147456, stream>>>(freq_data, iw_bf, s_hat, scal, xmp);
  conv_gemm8_k<<<512, 512, 131072, stream>>>(xmp, bt_conv, dcoefs, conv_b, out);
}

// Round 13
// 377.322 us; speedup vs baseline: 1.0974x; 1.0410x over previous
//
#include <hip/hip_runtime.h>

// ---------- types / helpers ----------
typedef __attribute__((ext_vector_type(4))) float f32x4;
typedef __attribute__((ext_vector_type(8))) __bf16 bf16x8;

__device__ __forceinline__ unsigned short f2bf(float f) {
  unsigned int u = __builtin_bit_cast(unsigned int, f);
  return (unsigned short)((u + 0x7FFFu + ((u >> 16) & 1u)) >> 16);  // RNE
}

__device__ __forceinline__ float sin2pi(float x) {  // sin(2*pi*x)
#if __has_builtin(__builtin_amdgcn_sinf) && __has_builtin(__builtin_amdgcn_fractf)
  return __builtin_amdgcn_sinf(__builtin_amdgcn_fractf(x));
#else
  return __sinf(x * 6.283185307179586f);
#endif
}

__device__ __forceinline__ void gll16(const void* g, void* l) {
  __builtin_amdgcn_global_load_lds(
      (const __attribute__((address_space(1))) void*)g,
      (__attribute__((address_space(3))) void*)l, 16, 0, 0);
}

template <int W>
__device__ __forceinline__ void vmwait() {
  if constexpr (W == 0) asm volatile("s_waitcnt vmcnt(0)" ::: "memory");
  else if constexpr (W == 2) asm volatile("s_waitcnt vmcnt(2)" ::: "memory");
  else if constexpr (W == 4) asm volatile("s_waitcnt vmcnt(4)" ::: "memory");
  else if constexpr (W == 6) asm volatile("s_waitcnt vmcnt(6)" ::: "memory");
  else if constexpr (W == 8) asm volatile("s_waitcnt vmcnt(8)" ::: "memory");
}

// compile-time memory fence (no instruction): stops hipcc moving LDS/global ops
// across raw s_barrier (raw barrier builtin has NO memory semantics at IR level).
#define CFENCE() asm volatile("" ::: "memory")

// ---------- fused independent preps (border / prep_freq / style / convw / iw_cast) ----------
// All blocks 256 threads; branches are block-uniform so per-branch __syncthreads is safe.
__global__ void fused_prep_k(const float* __restrict__ w, const float* __restrict__ affine_w,
                             const float* __restrict__ affine_b, const float* __restrict__ freqs,
                             const float* __restrict__ phases, const float* __restrict__ style_w,
                             const float* __restrict__ style_b, const float* __restrict__ conv_w,
                             const float* __restrict__ iw,
                             float4* __restrict__ freq_data, float* __restrict__ scal,
                             float* __restrict__ s_out, float* __restrict__ wsumT,
                             unsigned short* __restrict__ bt_conv,
                             unsigned short* __restrict__ iw_bf,
                             unsigned short* __restrict__ xmp) {
  const int bid = blockIdx.x, tid = threadIdx.x;
  if (bid < 1040) {
    // ---- border zero for padded xmp (16 b * 260 border px * 64 chunks = 266240) ----
    int idx = bid * 256 + tid;
    int chunk = idx & 63;
    int t = idx >> 6;
    int p = t % 260;
    int b = t / 260;
    int h, wq;
    if (p < 66) { h = 0; wq = p; }
    else if (p < 132) { h = 65; wq = p - 66; }
    else if (p < 196) { h = p - 131; wq = 0; }
    else { h = p - 195; wq = 65; }
    uint4 z; z.x = 0; z.y = 0; z.z = 0; z.w = 0;
    *(uint4*)&xmp[(((size_t)b * 66 + h) * 66 + wq) * 512 + chunk * 8] = z;
  } else if (bid < 1056) {
    // ---- prep_freq: per-(b,f) fourier data + effect_freq ----
    const int b = bid - 1040;
    const int wv = tid >> 6, lane = tid & 63;
    __shared__ float tdot[4];
    __shared__ float par[4];
    __shared__ float scnt;
    float sum = 0.f;
    for (int i = lane; i < 512; i += 64) sum += w[b * 512 + i] * affine_w[wv * 512 + i];
#pragma unroll
    for (int o = 32; o > 0; o >>= 1) sum += __shfl_down(sum, o);
    if (lane == 0) tdot[wv] = sum;
    if (tid == 0) scnt = 0.f;
    __syncthreads();
    if (tid == 0) {
      const float gain = 0.04419417382415922f;  // 1/sqrt(512)
      float t0 = tdot[0] * gain + affine_b[0];
      float t1 = tdot[1] * gain + affine_b[1];
      float t2 = tdot[2] * gain + affine_b[2];
      float t3 = tdot[3] * gain + affine_b[3];
      float inv = 1.f / sqrtf(t0 * t0 + t1 * t1);
      float c = t0 * inv, s = t1 * inv, tx = t2 * inv, ty = t3 * inv;
      par[0] = c; par[1] = s;
      par[2] = -c * tx + s * ty;   // shift0
      par[3] = -s * tx - c * ty;   // shift1
    }
    __syncthreads();
    const float c = par[0], s = par[1], sh0 = par[2], sh1 = par[3];
    float cnt = 0.f;
    for (int f = tid; f < 1024; f += 256) {
      float fx = freqs[2 * f], fy = freqs[2 * f + 1];
      float fb0 = fx * c + fy * s;
      float fb1 = fy * c - fx * s;
      float ph = phases[f] + fx * sh0 + fy * sh1;
      float nb = sqrtf(fb0 * fb0 + fb1 * fb1);
      float amp = fminf(fmaxf(1.f - (nb - 2.f) * (1.f / 30.f), 0.f), 1.f);
      float4 v; v.x = fb0; v.y = fb1; v.z = ph; v.w = amp;
      freq_data[(b << 10) + f] = v;
      if (sqrtf(fx * fx + fy * fy) < 2.f) cnt += 1.f;
    }
    if (b == 0) {
      atomicAdd(&scnt, cnt);   // integer-valued floats: exact, order-independent
      __syncthreads();
      if (tid == 0) scal[0] = 1.f / sqrtf(scnt);
    }
  } else if (bid < 1184) {
    // ---- style: s = fc(w, style_w, style_b); 4 lanes per output ----
    int gt = (bid - 1056) * 256 + tid;  // 32768 = 8192 outputs x 4 lanes
    int idx = gt >> 2, part = gt & 3;
    int b = idx >> 9, c = idx & 511;
    const float4* wr = (const float4*)(w + b * 512) + part * 32;
    const float4* sr = (const float4*)(style_w + (size_t)c * 512) + part * 32;
    float sum = 0.f;
#pragma unroll 4
    for (int i = 0; i < 32; ++i) {
      float4 a = wr[i], q = sr[i];
      sum += a.x * q.x + a.y * q.y + a.z * q.z + a.w * q.w;
    }
    sum += __shfl_xor(sum, 1);   // deterministic pairwise tree
    sum += __shfl_xor(sum, 2);
    if (part == 0) s_out[idx] = sum * 0.04419417382415922f + style_b[c];
  } else if (bid < 1696) {
    // ---- convw: normalize -> bt_conv (bf16 [o][kl*512+i]), wsumT[i][o] ----
    const int o = bid - 1184;
    __shared__ float red[256];
    float sum = 0.f;
    for (int i = tid; i < 4608; i += 256) { float v = conv_w[o * 4608 + i]; sum += v * v; }
    red[tid] = sum;
    __syncthreads();
    for (int off = 128; off > 0; off >>= 1) {
      if (tid < off) red[tid] += red[tid + off];
      __syncthreads();
    }
    const float rn = rsqrtf(red[0] * (1.f / 4608.f));
    for (int i = tid; i < 512; i += 256) {
      float sq = 0.f;
#pragma unroll
      for (int kl = 0; kl < 9; ++kl) {
        float v = conv_w[(o * 512 + i) * 9 + kl];
        sq += v * v;
        bt_conv[o * 4608 + kl * 512 + i] = f2bf(v * rn);
      }
      wsumT[i * 512 + o] = sq * rn * rn;  // transposed for coalesced dcoef reduce
    }
  } else {
    // ---- iw_cast: input_weight f32 -> bf16 (covers 524288 exactly) ----
    int i = (bid - 1696) * 256 + tid;
    iw_bf[i] = f2bf(iw[i]);
  }
}

// ---------- prep: s_hat + dcoefs; 8 blocks per batch (o-range split) ----------
__global__ void shat_dcoef_k(const float* __restrict__ s, const float* __restrict__ wsumT,
                             float* __restrict__ s_hat, float* __restrict__ dcoefs) {
  const int b = blockIdx.x >> 3, og = blockIdx.x & 7, tid = threadIdx.x;
  __shared__ float red[256];
  __shared__ float sh2[512];
  __shared__ float red2[256];
  float sum = 0.f;
  for (int i = tid; i < 8192; i += 256) { float v = s[i]; sum += v * v; }
  red[tid] = sum;
  __syncthreads();
  for (int off = 128; off > 0; off >>= 1) {
    if (tid < off) red[tid] += red[tid + off];
    __syncthreads();
  }
  const float inv_rms = rsqrtf(red[0] * (1.f / 8192.f));
  for (int c = tid; c < 512; c += 256) {
    float sh = s[b * 512 + c] * inv_rms;
    if (og == 0) s_hat[b * 512 + c] = sh;
    sh2[c] = sh * sh;
  }
  __syncthreads();
  const int o = (og << 6) + (tid & 63);
  const int ic = tid >> 6;  // 0..3: i-chunk of 128
  float acc = 0.f;
  for (int i = ic * 128; i < ic * 128 + 128; ++i) acc += wsumT[i * 512 + o] * sh2[i];
  red2[tid] = acc;
  __syncthreads();
  if (tid < 64) {
    float a = red2[tid] + red2[tid + 64] + red2[tid + 128] + red2[tid + 192];
    dcoefs[b * 512 + o] = rsqrtf(a + 1e-8f);
  }
}

// ---------- GEMM1 (R13): BN=512, single-barrier K-loop (conv-pattern), lA dbuf ----------
// M=65536, N=512, K=1024, BK=64. 512 thr / 8 waves (2Mx4N), wave tile 64x128.
// LDS: lA dbuf 2x16KB + lB dbuf 2x64KB = 160KB exactly (1 block/CU).
// Per kt: lgkm0 + vmcnt(0) + ONE barrier, then {issue B(kt+1) | MFMA(kt) | sin(kt+1)}.
// Dbuf proof (same as conv): reads of buf d sit between barrier(kt) and barrier(kt+1);
// all writes to buf d^1 (sin ds_write, B gll16) issue after barrier(kt) and are drained
// (lgkm0/vmcnt0) before barrier(kt+1), whose crossing releases them for reading.
__device__ __forceinline__ void sy_sgB(char* lB, const unsigned short* iw, int d,
                                       int rb, int kt, int lane, int lsw) {
  const unsigned short* src = iw + (size_t)(rb + (lane >> 3)) * 1024 + (kt << 6) + lsw;
  gll16(src, lB + d * 65536 + rb * 128);
}

__global__ __launch_bounds__(512, 2) void synth_gemm5_k(
    const float4* __restrict__ freq_data, const unsigned short* __restrict__ iw_bf,
    const float* __restrict__ s_hat, const float* __restrict__ scal,
    unsigned short* __restrict__ xmp) {
  extern __shared__ char sl[];
  char* lA = sl;            // 2 x (128 rows x 128B), XOR-swizzled sin tile
  char* lB = sl + 32768;    // 2 x (512 rows x 128B), XOR-swizzled via source
  const int bid = blockIdx.x;
  const int wg = (bid & 7) * 64 + (bid >> 3);  // XCD swizzle (512 % 8 == 0)
  const int m0 = wg << 7;
  const int b = m0 >> 12;
  const int hbase = (m0 >> 6) & 63;
  const int tid = threadIdx.x, lane = tid & 63, wv = tid >> 6;
  const int wm = (wv >> 2) << 6;        // 2 M-halves of 64 rows
  const int wn = (wv & 3) << 7;         // 4 N-quarters of 128 cols
  const int g = tid & 31;               // freq pair (2 freqs of 64)
  const int r0 = (tid >> 5) << 3;       // 8 rows per thread (of 128)
  const int lsw = (((lane & 7) ^ (lane >> 3)) << 3);
  const int aswz = (((lane >> 4) << 4)) ^ ((lane & 7) << 4);
  const int rowA = (wm + (lane & 15)) * 128;
  const int browB = wn + (lane & 15);
  f32x4 acc[4][8];
#pragma unroll
  for (int mi = 0; mi < 4; ++mi)
#pragma unroll
    for (int ni = 0; ni < 8; ++ni) { f32x4 z = {0.f, 0.f, 0.f, 0.f}; acc[mi][ni] = z; }
  const float gy0 = (hbase + 0.5f) * 0.015625f - 0.5f;
  const float gy1 = (hbase + 1.5f) * 0.015625f - 0.5f;

  // ---- prologue: stage B(0) -> lB[0]; compute sin(0) -> lA[0] ----
#pragma unroll
  for (int ig = 0; ig < 8; ++ig) sy_sgB(lB, iw_bf, 0, wv * 64 + ig * 8, 0, lane, lsw);
  {
    const float4* fdp = freq_data + (b << 10) + (g << 1);
    float4 fd0 = fdp[0], fd1 = fdp[1];
#pragma unroll
    for (int j = 0; j < 8; ++j) {
      const int r = r0 + j;
      const float gx = ((r & 63) + 0.5f) * 0.015625f - 0.5f;
      const float gy = (r >> 6) ? gy1 : gy0;
      ushort2 u;
      u.x = f2bf(sin2pi(gx * fd0.x + gy * fd0.y + fd0.z) * fd0.w);
      u.y = f2bf(sin2pi(gx * fd1.x + gy * fd1.y + fd1.z) * fd1.w);
      *(ushort2*)(lA + r * 128 + ((g << 2) ^ ((r & 7) << 4))) = u;
    }
  }

  for (int kt = 0; kt < 16; ++kt) {
    const int d = kt & 1, dn = d ^ 1;
    // own sin(kt) ds_writes + frag reads drained; B(kt) landed; all-wave rendezvous.
    asm volatile("s_waitcnt lgkmcnt(0)" ::: "memory");
    vmwait<0>();
    __builtin_amdgcn_s_barrier();
    CFENCE();
    __builtin_amdgcn_sched_barrier(0);

    // issue B(kt+1) -> lB[dn] (flies under MFMA + sin)
    if (kt < 15) {
#pragma unroll
      for (int ig = 0; ig < 8; ++ig)
        sy_sgB(lB, iw_bf, dn, wv * 64 + ig * 8, kt + 1, lane, lsw);
    }
    // MFMA(kt): af from lA[d], bq from lB[d]
    const char* pA = lA + d * 16384 + rowA;
    const char* pB = lB + d * 65536 + (size_t)browB * 128;
#pragma unroll
    for (int ks = 0; ks < 2; ++ks) {
      const int ao = aswz ^ (ks << 6);
      bf16x8 af[4], bq[8];
#pragma unroll
      for (int mi = 0; mi < 4; ++mi) af[mi] = *(const bf16x8*)(pA + mi * 2048 + ao);
#pragma unroll
      for (int ni = 0; ni < 8; ++ni) bq[ni] = *(const bf16x8*)(pB + ni * 2048 + ao);
      __builtin_amdgcn_s_setprio(1);
#pragma unroll
      for (int mi = 0; mi < 4; ++mi)
#pragma unroll
        for (int ni = 0; ni < 8; ++ni)
          acc[mi][ni] = __builtin_amdgcn_mfma_f32_16x16x32_bf16(af[mi], bq[ni], acc[mi][ni], 0, 0, 0);
      __builtin_amdgcn_s_setprio(0);
    }
    // sin(kt+1) -> lA[dn] (after this kt's reads; released by next barrier)
    if (kt < 15) {
      const float4* fdp = freq_data + (b << 10) + ((kt + 1) << 6) + (g << 1);
      float4 fd0 = fdp[0], fd1 = fdp[1];
#pragma unroll
      for (int j = 0; j < 8; ++j) {
        const int r = r0 + j;
        const float gx = ((r & 63) + 0.5f) * 0.015625f - 0.5f;
        const float gy = (r >> 6) ? gy1 : gy0;
        ushort2 u;
        u.x = f2bf(sin2pi(gx * fd0.x + gy * fd0.y + fd0.z) * fd0.w);
        u.y = f2bf(sin2pi(gx * fd1.x + gy * fd1.y + fd1.z) * fd1.w);
        *(ushort2*)(lA + dn * 16384 + r * 128 + ((g << 2) ^ ((r & 7) << 4))) = u;
      }
    }
    CFENCE();
  }
  // all waves done reading lA/lB before lT overwrite
  CFENCE();
  __builtin_amdgcn_s_barrier();
  CFENCE();

  // ---- epilogue: LDS transpose (row stride 520 ch = 1040B) -> coalesced stores ----
  const float inv_eff = scal[0];
  const int c_lo = lane & 15, r_hi = (lane >> 4) << 2;
  unsigned short* lT = (unsigned short*)sl;   // 128 x 520 x 2B = 133120 <= 163840
#pragma unroll
  for (int ni = 0; ni < 8; ++ni) {
    const int cc = wn + (ni << 4) + c_lo;
    const float sc = s_hat[b * 512 + cc] * inv_eff;
#pragma unroll
    for (int mi = 0; mi < 4; ++mi) {
#pragma unroll
      for (int j = 0; j < 4; ++j) {
        const int rr = wm + (mi << 4) + r_hi + j;
        lT[rr * 520 + cc] = f2bf(acc[mi][ni][j] * sc);
      }
    }
  }
  asm volatile("s_waitcnt lgkmcnt(0)" ::: "memory");  // own lT writes drained
  __builtin_amdgcn_s_barrier();                       // all waves' lT complete
  CFENCE();
#pragma unroll
  for (int it = 0; it < 16; ++it) {
    const int chunk = it * 512 + tid;   // 8192 chunks x 16B = 128 rows x 1KB
    const int row = chunk >> 6;
    const int co = (chunk & 63) << 3;   // 8 channels per 16B
    uint4 v = *(const uint4*)&lT[row * 520 + co];
    const int hp = hbase + (row >> 6) + 1;
    const int wp = (row & 63) + 1;
    *(uint4*)&xmp[(((size_t)b * 66 + hp) * 66 + wp) * 512 + co] = v;
  }
}

__device__ __forceinline__ float epi_act(float a, float dco, float cb) {
  float y = a * dco + cb;
  y = (y >= 0.f ? y : 0.2f * y) * 1.4142135623730951f;
  return fminf(fmaxf(y, -256.f), 256.f);
}

// ---------- GEMM2: 3x3 conv, 256x256 tile, BK=64, 8 waves (R8-verified) ----------
// kc-major tile order; single-barrier K-tile; all staging 1 tile ahead into D^1.
struct ConvCtx {
  const unsigned short* xmp;
  const unsigned short* bt;
  int n0, hb, b_img, lane;
  int lsw;
  int gB_rb0;
  int gA_lo;
  int gA_up;
};

__device__ __forceinline__ void tile_geom(int t, int& dh, int& dw, int& kc, int& koff) {
  const int kc8 = t / 9;
  const int off = t - 9 * kc8;
  dh = off / 3;
  dw = off - 3 * dh;
  kc = kc8 << 6;
  koff = off * 512 + kc;
}

__device__ __forceinline__ void sgA(char* lds, const ConvCtx& c, int d, int rb,
                                    int dh, int dw, int kc) {
  const int r = rb + (c.lane >> 3);
  const int h = c.hb + (r >> 6) + dh;
  const int w = (r & 63) + dw;
  const unsigned short* src = c.xmp + (((size_t)c.b_img * 66 + h) * 66 + w) * 512 + kc + c.lsw;
  gll16(src, lds + d * 32768 + rb * 128);
}

__device__ __forceinline__ void sgB(char* lds, const ConvCtx& c, int d, int rb, int koff) {
  const int row = c.n0 + rb + (c.lane >> 3);
  const unsigned short* src = c.bt + (size_t)row * 4608 + koff + c.lsw;
  gll16(src, lds + 65536 + d * 32768 + rb * 128);
}

template <bool STG>
__device__ __forceinline__ void conv_tile1(char* lds, const ConvCtx& c, f32x4 (&acc)[8][4],
                                           const char* pA, const char* pB, int aswz0, int t) {
  int dh1, dw1, kc1, koff1;
  tile_geom(t + 1, dh1, dw1, kc1, koff1);
  const int D = t & 1, Dn = D ^ 1;
  const int db = D << 15;
  const int a0 = aswz0, a1 = aswz0 ^ 64;

  vmwait<0>();                       // all stages for tile t (issued during t-1) landed
  __builtin_amdgcn_s_barrier();      // + every wave's stages landed, t-1 reads done
  CFENCE();
  __builtin_amdgcn_sched_barrier(0);

  bf16x8 bq[4], af[4];
  // ---- ks0, mh0 | issue B(t+1) -> D^1 ----
#pragma unroll
  for (int ni = 0; ni < 4; ++ni) bq[ni] = *(const bf16x8*)(pB + db + ni * 2048 + a0);
#pragma unroll
  for (int i = 0; i < 4; ++i) af[i] = *(const bf16x8*)(pA + db + i * 2048 + a0);
  if (STG) {
    sgB(lds, c, Dn, c.gB_rb0, koff1);      sgB(lds, c, Dn, c.gB_rb0 + 8, koff1);
    sgB(lds, c, Dn, c.gB_rb0 + 16, koff1); sgB(lds, c, Dn, c.gB_rb0 + 24, koff1);
  }
  __builtin_amdgcn_s_setprio(1);
#pragma unroll
  for (int i = 0; i < 4; ++i)
#pragma unroll
    for (int ni = 0; ni < 4; ++ni)
      acc[i][ni] = __builtin_amdgcn_mfma_f32_16x16x32_bf16(af[i], bq[ni], acc[i][ni], 0, 0, 0);
  __builtin_amdgcn_s_setprio(0);
  // ---- ks0, mh1 | issue A-up(t+1), A-lo(t+1) -> D^1 ----
#pragma unroll
  for (int i = 0; i < 4; ++i) af[i] = *(const bf16x8*)(pA + db + (4 + i) * 2048 + a0);
  if (STG) {
    sgA(lds, c, Dn, c.gA_up, dh1, dw1, kc1); sgA(lds, c, Dn, c.gA_up + 8, dh1, dw1, kc1);
    sgA(lds, c, Dn, c.gA_lo, dh1, dw1, kc1); sgA(lds, c, Dn, c.gA_lo + 8, dh1, dw1, kc1);
  }
  __builtin_amdgcn_s_setprio(1);
#pragma unroll
  for (int i = 0; i < 4; ++i)
#pragma unroll
    for (int ni = 0; ni < 4; ++ni)
      acc[4 + i][ni] = __builtin_amdgcn_mfma_f32_16x16x32_bf16(af[i], bq[ni], acc[4 + i][ni], 0, 0, 0);
  __builtin_amdgcn_s_setprio(0);
  // ---- ks1, mh0 ----
#pragma unroll
  for (int ni = 0; ni < 4; ++ni) bq[ni] = *(const bf16x8*)(pB + db + ni * 2048 + a1);
#pragma unroll
  for (int i = 0; i < 4; ++i) af[i] = *(const bf16x8*)(pA + db + i * 2048 + a1);
  __builtin_amdgcn_s_setprio(1);
#pragma unroll
  for (int i = 0; i < 4; ++i)
#pragma unroll
    for (int ni = 0; ni < 4; ++ni)
      acc[i][ni] = __builtin_amdgcn_mfma_f32_16x16x32_bf16(af[i], bq[ni], acc[i][ni], 0, 0, 0);
  __builtin_amdgcn_s_setprio(0);
  // ---- ks1, mh1 ----
#pragma unroll
  for (int i = 0; i < 4; ++i) af[i] = *(const bf16x8*)(pA + db + (4 + i) * 2048 + a1);
  __builtin_amdgcn_s_setprio(1);
#pragma unroll
  for (int i = 0; i < 4; ++i)
#pragma unroll
    for (int ni = 0; ni < 4; ++ni)
      acc[4 + i][ni] = __builtin_amdgcn_mfma_f32_16x16x32_bf16(af[i], bq[ni], acc[4 + i][ni], 0, 0, 0);
  __builtin_amdgcn_s_setprio(0);
  CFENCE();
}

__global__ __launch_bounds__(512, 2) void conv_gemm8_k(
    const unsigned short* __restrict__ xmp, const unsigned short* __restrict__ bt_conv,
    const float* __restrict__ dcoefs, const float* __restrict__ conv_b,
    float* __restrict__ out) {
  extern __shared__ char lds[];
  const int tid = threadIdx.x, lane = tid & 63, wv = tid >> 6;
  const int bid = blockIdx.x;
  const int wg = (bid & 7) * 64 + (bid >> 3);  // XCD-bijective swizzle (512 % 8 == 0)
  const int mt = wg >> 1, nt = wg & 1;
  const int m0 = mt << 8, n0 = nt << 8;
  const int b_img = m0 >> 12;
  const int hb = (m0 >> 6) & 63;
  const int wm = (wv >> 2) << 7, wn = (wv & 3) << 6;

  ConvCtx c;
  c.xmp = xmp; c.bt = bt_conv;
  c.n0 = n0; c.hb = hb; c.b_img = b_img; c.lane = lane;
  c.lsw = (((lane & 7) ^ (lane >> 3)) << 3);
  c.gB_rb0 = (((wv & 3) >> 1) << 7) + (((wv & 1) | ((wv >> 2) << 1)) << 5);
  c.gA_lo = wm + ((wv & 3) << 4);
  c.gA_up = c.gA_lo + 64;

  const char* pA = lds + (size_t)(wm + (lane & 15)) * 128;
  const char* pB = lds + 65536 + (size_t)(wn + (lane & 15)) * 128;
  const int aswz0 = (((lane >> 4) << 4)) ^ ((lane & 7) << 4);

  f32x4 acc[8][4];
#pragma unroll
  for (int mi = 0; mi < 8; ++mi)
#pragma unroll
    for (int ni = 0; ni < 4; ++ni) { f32x4 z = {0.f, 0.f, 0.f, 0.f}; acc[mi][ni] = z; }

  // Prologue: stage tile 0 (kc=0, off=0) fully into buf 0. Waited by tile 0's vmcnt(0).
  sgB(lds, c, 0, c.gB_rb0, 0);       sgB(lds, c, 0, c.gB_rb0 + 8, 0);
  sgB(lds, c, 0, c.gB_rb0 + 16, 0);  sgB(lds, c, 0, c.gB_rb0 + 24, 0);
  sgA(lds, c, 0, c.gA_up, 0, 0, 0);  sgA(lds, c, 0, c.gA_up + 8, 0, 0, 0);
  sgA(lds, c, 0, c.gA_lo, 0, 0, 0);  sgA(lds, c, 0, c.gA_lo + 8, 0, 0, 0);

  // 72 K-tiles, kc-major; one barrier + one vmcnt(0) per tile.
  for (int t = 0; t < 71; ++t) conv_tile1<true>(lds, c, acc, pA, pB, aswz0, t);
  conv_tile1<false>(lds, c, acc, pA, pB, aswz0, 71);

  // Epilogue
  const int c_lo = lane & 15, r_hi = (lane >> 4) << 2;
#pragma unroll
  for (int ni = 0; ni < 4; ++ni) {
    const int oo = n0 + wn + (ni << 4) + c_lo;
    const float dco = dcoefs[b_img * 512 + oo];
    const float cb = conv_b[oo];
#pragma unroll
    for (int mi = 0; mi < 8; ++mi) {
      const int rr = wm + (mi << 4) + r_hi;
      const int hh = hb + (rr >> 6);
      const int w0 = rr & 63;
      float4 v;
      v.x = epi_act(acc[mi][ni][0], dco, cb);
      v.y = epi_act(acc[mi][ni][1], dco, cb);
      v.z = epi_act(acc[mi][ni][2], dco, cb);
      v.w = epi_act(acc[mi][ni][3], dco, cb);
      *(float4*)&out[(((size_t)b_img * 512 + oo) * 64 + hh) * 64 + w0] = v;
    }
  }
}

// ---------- launch ----------
extern "C" void kernel_launch(void* const* d_in, const int* in_sizes, int n_in,
                              void* d_out, int out_size, void* d_ws, size_t ws_size,
                              hipStream_t stream) {
  (void)in_sizes; (void)n_in; (void)out_size;
  const float* w        = (const float*)d_in[0];
  const float* affine_w = (const float*)d_in[1];
  const float* affine_b = (const float*)d_in[2];
  const float* freqs    = (const float*)d_in[3];
  const float* phases   = (const float*)d_in[4];
  const float* input_weight = (const float*)d_in[5];
  const float* style_w  = (const float*)d_in[6];
  const float* style_b  = (const float*)d_in[7];
  const float* conv_w   = (const float*)d_in[8];
  const float* conv_b   = (const float*)d_in[9];
  float* out = (float*)d_out;

  char* p = (char*)d_ws;
  float4* freq_data = (float4*)p;               p += (size_t)16 * 1024 * 16;
  float* scal = (float*)p;                      p += 256;
  float* s_buf = (float*)p;                     p += 8192 * 4;
  float* s_hat = (float*)p;                     p += 8192 * 4;
  float* wsumT = (float*)p;                     p += (size_t)512 * 512 * 4;
  float* dcoefs = (float*)p;                    p += 8192 * 4;
  unsigned short* iw_bf = (unsigned short*)p;   p += (size_t)512 * 1024 * 2;
  unsigned short* bt_conv = (unsigned short*)p; p += (size_t)512 * 4608 * 2;
  unsigned short* xmp = (unsigned short*)p;     p += (size_t)16 * 66 * 66 * 512 * 2;
  if (ws_size < (size_t)(p - (char*)d_ws)) return;  // workspace too small: fail loudly

  (void)hipFuncSetAttribute((const void*)conv_gemm8_k,
                            hipFuncAttributeMaxDynamicSharedMemorySize, 131072);
  (void)hipFuncSetAttribute((const void*)synth_gemm5_k,
                            hipFuncAttributeMaxDynamicSharedMemorySize, 163840);

  fused_prep_k<<<3744, 256, 0, stream>>>(w, affine_w, affine_b, freqs, phases,
                                         style_w, style_b, conv_w, input_weight,
                                         freq_data, scal, s_buf, wsumT, bt_conv,
                                         iw_bf, xmp);
  shat_dcoef_k<<<128, 256, 0, stream>>>(s_buf, wsumT, s_hat, dcoefs);
  synth_gemm5_k<<<512, 512, 163840, stream>>>(freq_data, iw_bf, s_hat, scal, xmp);
  conv_gemm8_k<<<512, 512, 131072, stream>>>(xmp, bt_conv, dcoefs, conv_b, out);
}

// Round 14
// 348.897 us; speedup vs baseline: 1.1868x; 1.0815x over previous
//
#include <hip/hip_runtime.h>

// ---------- types / helpers ----------
typedef __attribute__((ext_vector_type(4))) float f32x4;
typedef __attribute__((ext_vector_type(8))) __bf16 bf16x8;

__device__ __forceinline__ unsigned short f2bf(float f) {
  unsigned int u = __builtin_bit_cast(unsigned int, f);
  return (unsigned short)((u + 0x7FFFu + ((u >> 16) & 1u)) >> 16);  // RNE
}

__device__ __forceinline__ float sin2pi(float x) {  // sin(2*pi*x)
#if __has_builtin(__builtin_amdgcn_sinf) && __has_builtin(__builtin_amdgcn_fractf)
  return __builtin_amdgcn_sinf(__builtin_amdgcn_fractf(x));
#else
  return __sinf(x * 6.283185307179586f);
#endif
}

__device__ __forceinline__ void gll16(const void* g, void* l) {
  __builtin_amdgcn_global_load_lds(
      (const __attribute__((address_space(1))) void*)g,
      (__attribute__((address_space(3))) void*)l, 16, 0, 0);
}

template <int W>
__device__ __forceinline__ void vmwait() {
  if constexpr (W == 0) asm volatile("s_waitcnt vmcnt(0)" ::: "memory");
  else if constexpr (W == 2) asm volatile("s_waitcnt vmcnt(2)" ::: "memory");
  else if constexpr (W == 4) asm volatile("s_waitcnt vmcnt(4)" ::: "memory");
  else if constexpr (W == 6) asm volatile("s_waitcnt vmcnt(6)" ::: "memory");
  else if constexpr (W == 8) asm volatile("s_waitcnt vmcnt(8)" ::: "memory");
}

// compile-time memory fence (no instruction): stops hipcc moving LDS/global ops
// across raw s_barrier (raw barrier builtin has NO memory semantics at IR level).
#define CFENCE() asm volatile("" ::: "memory")

// ---------- fused independent preps (border / prep_freq / style / convw / iw_cast) ----------
// All blocks 256 threads; branches are block-uniform so per-branch __syncthreads is safe.
__global__ void fused_prep_k(const float* __restrict__ w, const float* __restrict__ affine_w,
                             const float* __restrict__ affine_b, const float* __restrict__ freqs,
                             const float* __restrict__ phases, const float* __restrict__ style_w,
                             const float* __restrict__ style_b, const float* __restrict__ conv_w,
                             const float* __restrict__ iw,
                             float4* __restrict__ freq_data, float* __restrict__ scal,
                             float* __restrict__ s_out, float* __restrict__ wsumT,
                             unsigned short* __restrict__ bt_conv,
                             unsigned short* __restrict__ iw_bf,
                             unsigned short* __restrict__ xmp) {
  const int bid = blockIdx.x, tid = threadIdx.x;
  if (bid < 1040) {
    // ---- border zero for padded xmp (16 b * 260 border px * 64 chunks = 266240) ----
    int idx = bid * 256 + tid;
    int chunk = idx & 63;
    int t = idx >> 6;
    int p = t % 260;
    int b = t / 260;
    int h, wq;
    if (p < 66) { h = 0; wq = p; }
    else if (p < 132) { h = 65; wq = p - 66; }
    else if (p < 196) { h = p - 131; wq = 0; }
    else { h = p - 195; wq = 65; }
    uint4 z; z.x = 0; z.y = 0; z.z = 0; z.w = 0;
    *(uint4*)&xmp[(((size_t)b * 66 + h) * 66 + wq) * 512 + chunk * 8] = z;
  } else if (bid < 1056) {
    // ---- prep_freq: per-(b,f) fourier data + effect_freq ----
    const int b = bid - 1040;
    const int wv = tid >> 6, lane = tid & 63;
    __shared__ float tdot[4];
    __shared__ float par[4];
    __shared__ float scnt;
    float sum = 0.f;
    for (int i = lane; i < 512; i += 64) sum += w[b * 512 + i] * affine_w[wv * 512 + i];
#pragma unroll
    for (int o = 32; o > 0; o >>= 1) sum += __shfl_down(sum, o);
    if (lane == 0) tdot[wv] = sum;
    if (tid == 0) scnt = 0.f;
    __syncthreads();
    if (tid == 0) {
      const float gain = 0.04419417382415922f;  // 1/sqrt(512)
      float t0 = tdot[0] * gain + affine_b[0];
      float t1 = tdot[1] * gain + affine_b[1];
      float t2 = tdot[2] * gain + affine_b[2];
      float t3 = tdot[3] * gain + affine_b[3];
      float inv = 1.f / sqrtf(t0 * t0 + t1 * t1);
      float c = t0 * inv, s = t1 * inv, tx = t2 * inv, ty = t3 * inv;
      par[0] = c; par[1] = s;
      par[2] = -c * tx + s * ty;   // shift0
      par[3] = -s * tx - c * ty;   // shift1
    }
    __syncthreads();
    const float c = par[0], s = par[1], sh0 = par[2], sh1 = par[3];
    float cnt = 0.f;
    for (int f = tid; f < 1024; f += 256) {
      float fx = freqs[2 * f], fy = freqs[2 * f + 1];
      float fb0 = fx * c + fy * s;
      float fb1 = fy * c - fx * s;
      float ph = phases[f] + fx * sh0 + fy * sh1;
      float nb = sqrtf(fb0 * fb0 + fb1 * fb1);
      float amp = fminf(fmaxf(1.f - (nb - 2.f) * (1.f / 30.f), 0.f), 1.f);
      float4 v; v.x = fb0; v.y = fb1; v.z = ph; v.w = amp;
      freq_data[(b << 10) + f] = v;
      if (sqrtf(fx * fx + fy * fy) < 2.f) cnt += 1.f;
    }
    if (b == 0) {
      atomicAdd(&scnt, cnt);   // integer-valued floats: exact, order-independent
      __syncthreads();
      if (tid == 0) scal[0] = 1.f / sqrtf(scnt);
    }
  } else if (bid < 1184) {
    // ---- style: s = fc(w, style_w, style_b); 4 lanes per output ----
    int gt = (bid - 1056) * 256 + tid;  // 32768 = 8192 outputs x 4 lanes
    int idx = gt >> 2, part = gt & 3;
    int b = idx >> 9, c = idx & 511;
    const float4* wr = (const float4*)(w + b * 512) + part * 32;
    const float4* sr = (const float4*)(style_w + (size_t)c * 512) + part * 32;
    float sum = 0.f;
#pragma unroll 4
    for (int i = 0; i < 32; ++i) {
      float4 a = wr[i], q = sr[i];
      sum += a.x * q.x + a.y * q.y + a.z * q.z + a.w * q.w;
    }
    sum += __shfl_xor(sum, 1);   // deterministic pairwise tree
    sum += __shfl_xor(sum, 2);
    if (part == 0) s_out[idx] = sum * 0.04419417382415922f + style_b[c];
  } else if (bid < 1696) {
    // ---- convw: normalize -> bt_conv (bf16 [o][kl*512+i]), wsumT[i][o] ----
    const int o = bid - 1184;
    __shared__ float red[256];
    float sum = 0.f;
    for (int i = tid; i < 4608; i += 256) { float v = conv_w[o * 4608 + i]; sum += v * v; }
    red[tid] = sum;
    __syncthreads();
    for (int off = 128; off > 0; off >>= 1) {
      if (tid < off) red[tid] += red[tid + off];
      __syncthreads();
    }
    const float rn = rsqrtf(red[0] * (1.f / 4608.f));
    for (int i = tid; i < 512; i += 256) {
      float sq = 0.f;
#pragma unroll
      for (int kl = 0; kl < 9; ++kl) {
        float v = conv_w[(o * 512 + i) * 9 + kl];
        sq += v * v;
        bt_conv[o * 4608 + kl * 512 + i] = f2bf(v * rn);
      }
      wsumT[i * 512 + o] = sq * rn * rn;  // transposed for coalesced dcoef reduce
    }
  } else {
    // ---- iw_cast: input_weight f32 -> bf16 (covers 524288 exactly) ----
    int i = (bid - 1696) * 256 + tid;
    iw_bf[i] = f2bf(iw[i]);
  }
}

// ---------- GEMM1 (R14): BN=512, single-barrier K-loop; inline inv_rms; ----------
// blocks 0..511: GEMM (as R13, s_hat computed on the fly from s_buf);
// blocks 512..639: dcoefs (16 b x 8 o-groups), no cross-block dependency:
// GEMM blocks never read dcoefs; dcoef blocks never touch xmp. dcoefs consumed
// only by the NEXT kernel (conv).
__device__ __forceinline__ void sy_sgB(char* lB, const unsigned short* iw, int d,
                                       int rb, int kt, int lane, int lsw) {
  const unsigned short* src = iw + (size_t)(rb + (lane >> 3)) * 1024 + (kt << 6) + lsw;
  gll16(src, lB + d * 65536 + rb * 128);
}

__global__ __launch_bounds__(512, 2) void synth_gemm6_k(
    const float4* __restrict__ freq_data, const unsigned short* __restrict__ iw_bf,
    const float* __restrict__ s_buf, const float* __restrict__ scal,
    const float* __restrict__ wsumT, float* __restrict__ dcoefs,
    unsigned short* __restrict__ xmp) {
  extern __shared__ char sl[];
  const int bid = blockIdx.x;
  const int tid = threadIdx.x, lane = tid & 63, wv = tid >> 6;

  if (bid >= 512) {
    // ---- dcoefs branch (512 threads): b = og>>3? no: 128 blocks = 16b x 8og ----
    const int bb = (bid - 512) >> 3, og = (bid - 512) & 7;
    float* red = (float*)sl;            // 512 f
    float* sh2 = (float*)(sl + 2048);   // 512 f
    float* red2 = (float*)(sl + 4096);  // 512 f
    float sum = 0.f;
    for (int i = tid; i < 8192; i += 512) { float v = s_buf[i]; sum += v * v; }
    red[tid] = sum;
    __syncthreads();
    for (int off = 256; off > 0; off >>= 1) {
      if (tid < off) red[tid] += red[tid + off];
      __syncthreads();
    }
    const float inv_rms = rsqrtf(red[0] * (1.f / 8192.f));
    {
      float sh = s_buf[bb * 512 + tid] * inv_rms;  // tid in [0,512): one c each
      sh2[tid] = sh * sh;
    }
    __syncthreads();
    const int o = (og << 6) + (tid & 63);
    const int ic = tid >> 6;  // 0..7: i-chunk of 64
    float acc = 0.f;
    for (int i = ic * 64; i < ic * 64 + 64; ++i) acc += wsumT[i * 512 + o] * sh2[i];
    red2[tid] = acc;
    __syncthreads();
    if (tid < 64) {
      float a = 0.f;
#pragma unroll
      for (int k = 0; k < 8; ++k) a += red2[tid + (k << 6)];
      dcoefs[bb * 512 + (og << 6) + tid] = rsqrtf(a + 1e-8f);
    }
    return;
  }

  // ---- GEMM branch ----
  char* lA = sl;            // 2 x (128 rows x 128B), XOR-swizzled sin tile
  char* lB = sl + 32768;    // 2 x (512 rows x 128B), XOR-swizzled via source
  const int wg = (bid & 7) * 64 + (bid >> 3);  // XCD swizzle (512 % 8 == 0)
  const int m0 = wg << 7;
  const int b = m0 >> 12;
  const int hbase = (m0 >> 6) & 63;
  const int wm = (wv >> 2) << 6;        // 2 M-halves of 64 rows
  const int wn = (wv & 3) << 7;         // 4 N-quarters of 128 cols
  const int g = tid & 31;               // freq pair (2 freqs of 64)
  const int r0 = (tid >> 5) << 3;       // 8 rows per thread (of 128)
  const int lsw = (((lane & 7) ^ (lane >> 3)) << 3);
  const int aswz = (((lane >> 4) << 4)) ^ ((lane & 7) << 4);
  const int rowA = (wm + (lane & 15)) * 128;
  const int browB = wn + (lane & 15);
  f32x4 acc[4][8];
#pragma unroll
  for (int mi = 0; mi < 4; ++mi)
#pragma unroll
    for (int ni = 0; ni < 8; ++ni) { f32x4 z = {0.f, 0.f, 0.f, 0.f}; acc[mi][ni] = z; }
  const float gy0 = (hbase + 0.5f) * 0.015625f - 0.5f;
  const float gy1 = (hbase + 1.5f) * 0.015625f - 0.5f;

  // ---- prologue: stage B(0) -> lB[0]; compute sin(0) -> lA[0] ----
#pragma unroll
  for (int ig = 0; ig < 8; ++ig) sy_sgB(lB, iw_bf, 0, wv * 64 + ig * 8, 0, lane, lsw);
  {
    const float4* fdp = freq_data + (b << 10) + (g << 1);
    float4 fd0 = fdp[0], fd1 = fdp[1];
#pragma unroll
    for (int j = 0; j < 8; ++j) {
      const int r = r0 + j;
      const float gx = ((r & 63) + 0.5f) * 0.015625f - 0.5f;
      const float gy = (r >> 6) ? gy1 : gy0;
      ushort2 u;
      u.x = f2bf(sin2pi(gx * fd0.x + gy * fd0.y + fd0.z) * fd0.w);
      u.y = f2bf(sin2pi(gx * fd1.x + gy * fd1.y + fd1.z) * fd1.w);
      *(ushort2*)(lA + r * 128 + ((g << 2) ^ ((r & 7) << 4))) = u;
    }
  }

  for (int kt = 0; kt < 16; ++kt) {
    const int d = kt & 1, dn = d ^ 1;
    // own sin(kt) ds_writes + frag reads drained; B(kt) landed; all-wave rendezvous.
    asm volatile("s_waitcnt lgkmcnt(0)" ::: "memory");
    vmwait<0>();
    __builtin_amdgcn_s_barrier();
    CFENCE();
    __builtin_amdgcn_sched_barrier(0);

    // issue B(kt+1) -> lB[dn] (flies under MFMA + sin)
    if (kt < 15) {
#pragma unroll
      for (int ig = 0; ig < 8; ++ig)
        sy_sgB(lB, iw_bf, dn, wv * 64 + ig * 8, kt + 1, lane, lsw);
    }
    // MFMA(kt): af from lA[d], bq from lB[d]
    const char* pA = lA + d * 16384 + rowA;
    const char* pB = lB + d * 65536 + (size_t)browB * 128;
#pragma unroll
    for (int ks = 0; ks < 2; ++ks) {
      const int ao = aswz ^ (ks << 6);
      bf16x8 af[4], bq[8];
#pragma unroll
      for (int mi = 0; mi < 4; ++mi) af[mi] = *(const bf16x8*)(pA + mi * 2048 + ao);
#pragma unroll
      for (int ni = 0; ni < 8; ++ni) bq[ni] = *(const bf16x8*)(pB + ni * 2048 + ao);
      __builtin_amdgcn_s_setprio(1);
#pragma unroll
      for (int mi = 0; mi < 4; ++mi)
#pragma unroll
        for (int ni = 0; ni < 8; ++ni)
          acc[mi][ni] = __builtin_amdgcn_mfma_f32_16x16x32_bf16(af[mi], bq[ni], acc[mi][ni], 0, 0, 0);
      __builtin_amdgcn_s_setprio(0);
    }
    // sin(kt+1) -> lA[dn] (after this kt's reads; released by next barrier)
    if (kt < 15) {
      const float4* fdp = freq_data + (b << 10) + ((kt + 1) << 6) + (g << 1);
      float4 fd0 = fdp[0], fd1 = fdp[1];
#pragma unroll
      for (int j = 0; j < 8; ++j) {
        const int r = r0 + j;
        const float gx = ((r & 63) + 0.5f) * 0.015625f - 0.5f;
        const float gy = (r >> 6) ? gy1 : gy0;
        ushort2 u;
        u.x = f2bf(sin2pi(gx * fd0.x + gy * fd0.y + fd0.z) * fd0.w);
        u.y = f2bf(sin2pi(gx * fd1.x + gy * fd1.y + fd1.z) * fd1.w);
        *(ushort2*)(lA + dn * 16384 + r * 128 + ((g << 2) ^ ((r & 7) << 4))) = u;
      }
    }
    CFENCE();
  }
  // all waves done reading lA/lB before LDS reuse below
  CFENCE();
  __builtin_amdgcn_s_barrier();
  CFENCE();

  // ---- inline inv_rms over s_buf (deterministic wave-reduce + fixed 8-sum) ----
  float ps = 0.f;
  for (int i = tid; i < 8192; i += 512) { float v = s_buf[i]; ps += v * v; }
#pragma unroll
  for (int o2 = 32; o2 > 0; o2 >>= 1) ps += __shfl_xor(ps, o2);
  float* rsw = (float*)(sl + 163776);   // 8 floats, above lT (ends 133120)
  if (lane == 0) rsw[wv] = ps;
  __syncthreads();
  const float inv_rms = rsqrtf((rsw[0] + rsw[1] + rsw[2] + rsw[3] +
                                rsw[4] + rsw[5] + rsw[6] + rsw[7]) * (1.f / 8192.f));

  // ---- epilogue: LDS transpose (row stride 520 ch = 1040B) -> coalesced stores ----
  const float inv_eff = scal[0];
  const int c_lo = lane & 15, r_hi = (lane >> 4) << 2;
  unsigned short* lT = (unsigned short*)sl;   // 128 x 520 x 2B = 133120 <= 163840
#pragma unroll
  for (int ni = 0; ni < 8; ++ni) {
    const int cc = wn + (ni << 4) + c_lo;
    const float sc = s_buf[b * 512 + cc] * inv_rms * inv_eff;
#pragma unroll
    for (int mi = 0; mi < 4; ++mi) {
#pragma unroll
      for (int j = 0; j < 4; ++j) {
        const int rr = wm + (mi << 4) + r_hi + j;
        lT[rr * 520 + cc] = f2bf(acc[mi][ni][j] * sc);
      }
    }
  }
  asm volatile("s_waitcnt lgkmcnt(0)" ::: "memory");  // own lT writes drained
  __builtin_amdgcn_s_barrier();                       // all waves' lT complete
  CFENCE();
#pragma unroll
  for (int it = 0; it < 16; ++it) {
    const int chunk = it * 512 + tid;   // 8192 chunks x 16B = 128 rows x 1KB
    const int row = chunk >> 6;
    const int co = (chunk & 63) << 3;   // 8 channels per 16B
    uint4 v = *(const uint4*)&lT[row * 520 + co];
    const int hp = hbase + (row >> 6) + 1;
    const int wp = (row & 63) + 1;
    *(uint4*)&xmp[(((size_t)b * 66 + hp) * 66 + wp) * 512 + co] = v;
  }
}

__device__ __forceinline__ float epi_act(float a, float dco, float cb) {
  float y = a * dco + cb;
  y = (y >= 0.f ? y : 0.2f * y) * 1.4142135623730951f;
  return fminf(fmaxf(y, -256.f), 256.f);
}

// ---------- GEMM2: 3x3 conv, 256x256 tile, BK=64, 8 waves (R8-verified) ----------
// kc-major tile order; single-barrier K-tile; all staging 1 tile ahead into D^1.
struct ConvCtx {
  const unsigned short* xmp;
  const unsigned short* bt;
  int n0, hb, b_img, lane;
  int lsw;
  int gB_rb0;
  int gA_lo;
  int gA_up;
};

__device__ __forceinline__ void tile_geom(int t, int& dh, int& dw, int& kc, int& koff) {
  const int kc8 = t / 9;
  const int off = t - 9 * kc8;
  dh = off / 3;
  dw = off - 3 * dh;
  kc = kc8 << 6;
  koff = off * 512 + kc;
}

__device__ __forceinline__ void sgA(char* lds, const ConvCtx& c, int d, int rb,
                                    int dh, int dw, int kc) {
  const int r = rb + (c.lane >> 3);
  const int h = c.hb + (r >> 6) + dh;
  const int w = (r & 63) + dw;
  const unsigned short* src = c.xmp + (((size_t)c.b_img * 66 + h) * 66 + w) * 512 + kc + c.lsw;
  gll16(src, lds + d * 32768 + rb * 128);
}

__device__ __forceinline__ void sgB(char* lds, const ConvCtx& c, int d, int rb, int koff) {
  const int row = c.n0 + rb + (c.lane >> 3);
  const unsigned short* src = c.bt + (size_t)row * 4608 + koff + c.lsw;
  gll16(src, lds + 65536 + d * 32768 + rb * 128);
}

template <bool STG>
__device__ __forceinline__ void conv_tile1(char* lds, const ConvCtx& c, f32x4 (&acc)[8][4],
                                           const char* pA, const char* pB, int aswz0, int t) {
  int dh1, dw1, kc1, koff1;
  tile_geom(t + 1, dh1, dw1, kc1, koff1);
  const int D = t & 1, Dn = D ^ 1;
  const int db = D << 15;
  const int a0 = aswz0, a1 = aswz0 ^ 64;

  vmwait<0>();                       // all stages for tile t (issued during t-1) landed
  __builtin_amdgcn_s_barrier();      // + every wave's stages landed, t-1 reads done
  CFENCE();
  __builtin_amdgcn_sched_barrier(0);

  bf16x8 bq[4], af[4];
  // ---- ks0, mh0 | issue B(t+1) -> D^1 ----
#pragma unroll
  for (int ni = 0; ni < 4; ++ni) bq[ni] = *(const bf16x8*)(pB + db + ni * 2048 + a0);
#pragma unroll
  for (int i = 0; i < 4; ++i) af[i] = *(const bf16x8*)(pA + db + i * 2048 + a0);
  if (STG) {
    sgB(lds, c, Dn, c.gB_rb0, koff1);      sgB(lds, c, Dn, c.gB_rb0 + 8, koff1);
    sgB(lds, c, Dn, c.gB_rb0 + 16, koff1); sgB(lds, c, Dn, c.gB_rb0 + 24, koff1);
  }
  __builtin_amdgcn_s_setprio(1);
#pragma unroll
  for (int i = 0; i < 4; ++i)
#pragma unroll
    for (int ni = 0; ni < 4; ++ni)
      acc[i][ni] = __builtin_amdgcn_mfma_f32_16x16x32_bf16(af[i], bq[ni], acc[i][ni], 0, 0, 0);
  __builtin_amdgcn_s_setprio(0);
  // ---- ks0, mh1 | issue A-up(t+1), A-lo(t+1) -> D^1 ----
#pragma unroll
  for (int i = 0; i < 4; ++i) af[i] = *(const bf16x8*)(pA + db + (4 + i) * 2048 + a0);
  if (STG) {
    sgA(lds, c, Dn, c.gA_up, dh1, dw1, kc1); sgA(lds, c, Dn, c.gA_up + 8, dh1, dw1, kc1);
    sgA(lds, c, Dn, c.gA_lo, dh1, dw1, kc1); sgA(lds, c, Dn, c.gA_lo + 8, dh1, dw1, kc1);
  }
  __builtin_amdgcn_s_setprio(1);
#pragma unroll
  for (int i = 0; i < 4; ++i)
#pragma unroll
    for (int ni = 0; ni < 4; ++ni)
      acc[4 + i][ni] = __builtin_amdgcn_mfma_f32_16x16x32_bf16(af[i], bq[ni], acc[4 + i][ni], 0, 0, 0);
  __builtin_amdgcn_s_setprio(0);
  // ---- ks1, mh0 ----
#pragma unroll
  for (int ni = 0; ni < 4; ++ni) bq[ni] = *(const bf16x8*)(pB + db + ni * 2048 + a1);
#pragma unroll
  for (int i = 0; i < 4; ++i) af[i] = *(const bf16x8*)(pA + db + i * 2048 + a1);
  __builtin_amdgcn_s_setprio(1);
#pragma unroll
  for (int i = 0; i < 4; ++i)
#pragma unroll
    for (int ni = 0; ni < 4; ++ni)
      acc[i][ni] = __builtin_amdgcn_mfma_f32_16x16x32_bf16(af[i], bq[ni], acc[i][ni], 0, 0, 0);
  __builtin_amdgcn_s_setprio(0);
  // ---- ks1, mh1 ----
#pragma unroll
  for (int i = 0; i < 4; ++i) af[i] = *(const bf16x8*)(pA + db + (4 + i) * 2048 + a1);
  __builtin_amdgcn_s_setprio(1);
#pragma unroll
  for (int i = 0; i < 4; ++i)
#pragma unroll
    for (int ni = 0; ni < 4; ++ni)
      acc[4 + i][ni] = __builtin_amdgcn_mfma_f32_16x16x32_bf16(af[i], bq[ni], acc[4 + i][ni], 0, 0, 0);
  __builtin_amdgcn_s_setprio(0);
  CFENCE();
}

__global__ __launch_bounds__(512, 2) void conv_gemm8_k(
    const unsigned short* __restrict__ xmp, const unsigned short* __restrict__ bt_conv,
    const float* __restrict__ dcoefs, const float* __restrict__ conv_b,
    float* __restrict__ out) {
  extern __shared__ char lds[];
  const int tid = threadIdx.x, lane = tid & 63, wv = tid >> 6;
  const int bid = blockIdx.x;
  const int wg = (bid & 7) * 64 + (bid >> 3);  // XCD-bijective swizzle (512 % 8 == 0)
  const int mt = wg >> 1, nt = wg & 1;
  const int m0 = mt << 8, n0 = nt << 8;
  const int b_img = m0 >> 12;
  const int hb = (m0 >> 6) & 63;
  const int wm = (wv >> 2) << 7, wn = (wv & 3) << 6;

  ConvCtx c;
  c.xmp = xmp; c.bt = bt_conv;
  c.n0 = n0; c.hb = hb; c.b_img = b_img; c.lane = lane;
  c.lsw = (((lane & 7) ^ (lane >> 3)) << 3);
  c.gB_rb0 = (((wv & 3) >> 1) << 7) + (((wv & 1) | ((wv >> 2) << 1)) << 5);
  c.gA_lo = wm + ((wv & 3) << 4);
  c.gA_up = c.gA_lo + 64;

  const char* pA = lds + (size_t)(wm + (lane & 15)) * 128;
  const char* pB = lds + 65536 + (size_t)(wn + (lane & 15)) * 128;
  const int aswz0 = (((lane >> 4) << 4)) ^ ((lane & 7) << 4);

  f32x4 acc[8][4];
#pragma unroll
  for (int mi = 0; mi < 8; ++mi)
#pragma unroll
    for (int ni = 0; ni < 4; ++ni) { f32x4 z = {0.f, 0.f, 0.f, 0.f}; acc[mi][ni] = z; }

  // Prologue: stage tile 0 (kc=0, off=0) fully into buf 0. Waited by tile 0's vmcnt(0).
  sgB(lds, c, 0, c.gB_rb0, 0);       sgB(lds, c, 0, c.gB_rb0 + 8, 0);
  sgB(lds, c, 0, c.gB_rb0 + 16, 0);  sgB(lds, c, 0, c.gB_rb0 + 24, 0);
  sgA(lds, c, 0, c.gA_up, 0, 0, 0);  sgA(lds, c, 0, c.gA_up + 8, 0, 0, 0);
  sgA(lds, c, 0, c.gA_lo, 0, 0, 0);  sgA(lds, c, 0, c.gA_lo + 8, 0, 0, 0);

  // 72 K-tiles, kc-major; one barrier + one vmcnt(0) per tile.
  for (int t = 0; t < 71; ++t) conv_tile1<true>(lds, c, acc, pA, pB, aswz0, t);
  conv_tile1<false>(lds, c, acc, pA, pB, aswz0, 71);

  // Epilogue
  const int c_lo = lane & 15, r_hi = (lane >> 4) << 2;
#pragma unroll
  for (int ni = 0; ni < 4; ++ni) {
    const int oo = n0 + wn + (ni << 4) + c_lo;
    const float dco = dcoefs[b_img * 512 + oo];
    const float cb = conv_b[oo];
#pragma unroll
    for (int mi = 0; mi < 8; ++mi) {
      const int rr = wm + (mi << 4) + r_hi;
      const int hh = hb + (rr >> 6);
      const int w0 = rr & 63;
      float4 v;
      v.x = epi_act(acc[mi][ni][0], dco, cb);
      v.y = epi_act(acc[mi][ni][1], dco, cb);
      v.z = epi_act(acc[mi][ni][2], dco, cb);
      v.w = epi_act(acc[mi][ni][3], dco, cb);
      *(float4*)&out[(((size_t)b_img * 512 + oo) * 64 + hh) * 64 + w0] = v;
    }
  }
}

// ---------- launch ----------
extern "C" void kernel_launch(void* const* d_in, const int* in_sizes, int n_in,
                              void* d_out, int out_size, void* d_ws, size_t ws_size,
                              hipStream_t stream) {
  (void)in_sizes; (void)n_in; (void)out_size;
  const float* w        = (const float*)d_in[0];
  const float* affine_w = (const float*)d_in[1];
  const float* affine_b = (const float*)d_in[2];
  const float* freqs    = (const float*)d_in[3];
  const float* phases   = (const float*)d_in[4];
  const float* input_weight = (const float*)d_in[5];
  const float* style_w  = (const float*)d_in[6];
  const float* style_b  = (const float*)d_in[7];
  const float* conv_w   = (const float*)d_in[8];
  const float* conv_b   = (const float*)d_in[9];
  float* out = (float*)d_out;

  char* p = (char*)d_ws;
  float4* freq_data = (float4*)p;               p += (size_t)16 * 1024 * 16;
  float* scal = (float*)p;                      p += 256;
  float* s_buf = (float*)p;                     p += 8192 * 4;
  float* s_hat = (float*)p;                     p += 8192 * 4;   // unused (kept for layout)
  float* wsumT = (float*)p;                     p += (size_t)512 * 512 * 4;
  float* dcoefs = (float*)p;                    p += 8192 * 4;
  unsigned short* iw_bf = (unsigned short*)p;   p += (size_t)512 * 1024 * 2;
  unsigned short* bt_conv = (unsigned short*)p; p += (size_t)512 * 4608 * 2;
  unsigned short* xmp = (unsigned short*)p;     p += (size_t)16 * 66 * 66 * 512 * 2;
  if (ws_size < (size_t)(p - (char*)d_ws)) return;  // workspace too small: fail loudly
  (void)s_hat;

  (void)hipFuncSetAttribute((const void*)conv_gemm8_k,
                            hipFuncAttributeMaxDynamicSharedMemorySize, 131072);
  (void)hipFuncSetAttribute((const void*)synth_gemm6_k,
                            hipFuncAttributeMaxDynamicSharedMemorySize, 163840);

  fused_prep_k<<<3744, 256, 0, stream>>>(w, affine_w, affine_b, freqs, phases,
                                         style_w, style_b, conv_w, input_weight,
                                         freq_data, scal, s_buf, wsumT, bt_conv,
                                         iw_bf, xmp);
  synth_gemm6_k<<<640, 512, 163840, stream>>>(freq_data, iw_bf, s_buf, scal,
                                              wsumT, dcoefs, xmp);
  conv_gemm8_k<<<512, 512, 131072, stream>>>(xmp, bt_conv, dcoefs, conv_b, out);
}

// Round 15
// 348.098 us; speedup vs baseline: 1.1895x; 1.0023x over previous
//
#include <hip/hip_runtime.h>

// ---------- types / helpers ----------
typedef __attribute__((ext_vector_type(4))) float f32x4;
typedef __attribute__((ext_vector_type(8))) __bf16 bf16x8;

__device__ __forceinline__ unsigned short f2bf(float f) {
  unsigned int u = __builtin_bit_cast(unsigned int, f);
  return (unsigned short)((u + 0x7FFFu + ((u >> 16) & 1u)) >> 16);  // RNE
}

__device__ __forceinline__ float sin2pi(float x) {  // sin(2*pi*x)
#if __has_builtin(__builtin_amdgcn_sinf) && __has_builtin(__builtin_amdgcn_fractf)
  return __builtin_amdgcn_sinf(__builtin_amdgcn_fractf(x));
#else
  return __sinf(x * 6.283185307179586f);
#endif
}

__device__ __forceinline__ void gll16(const void* g, void* l) {
  __builtin_amdgcn_global_load_lds(
      (const __attribute__((address_space(1))) void*)g,
      (__attribute__((address_space(3))) void*)l, 16, 0, 0);
}

template <int W>
__device__ __forceinline__ void vmwait() {
  if constexpr (W == 0) asm volatile("s_waitcnt vmcnt(0)" ::: "memory");
  else if constexpr (W == 2) asm volatile("s_waitcnt vmcnt(2)" ::: "memory");
  else if constexpr (W == 4) asm volatile("s_waitcnt vmcnt(4)" ::: "memory");
  else if constexpr (W == 6) asm volatile("s_waitcnt vmcnt(6)" ::: "memory");
  else if constexpr (W == 8) asm volatile("s_waitcnt vmcnt(8)" ::: "memory");
}

// compile-time memory fence (no instruction): stops hipcc moving LDS/global ops
// across raw s_barrier (raw barrier builtin has NO memory semantics at IR level).
#define CFENCE() asm volatile("" ::: "memory")

// ---------- fused preps feeding synth: prep_freq / style / iw_cast / convw ----------
// (convw feeds conv + dcoef ride-alongs in the NEXT launch, so it must finish here.
//  LDS-stash: conv_w row read ONCE coalesced; 2nd pass reads LDS, not global.)
__global__ void fused_prep_k(const float* __restrict__ w, const float* __restrict__ affine_w,
                             const float* __restrict__ affine_b, const float* __restrict__ freqs,
                             const float* __restrict__ phases, const float* __restrict__ style_w,
                             const float* __restrict__ style_b, const float* __restrict__ conv_w,
                             const float* __restrict__ iw,
                             float4* __restrict__ freq_data, float* __restrict__ scal,
                             float* __restrict__ s_out, float* __restrict__ wsumT,
                             unsigned short* __restrict__ bt_conv,
                             unsigned short* __restrict__ iw_bf) {
  const int bid = blockIdx.x, tid = threadIdx.x;
  if (bid < 16) {
    // ---- prep_freq: per-(b,f) fourier data + effect_freq ----
    const int b = bid;
    const int wv = tid >> 6, lane = tid & 63;
    __shared__ float tdot[4];
    __shared__ float par[4];
    __shared__ float scnt;
    float sum = 0.f;
    for (int i = lane; i < 512; i += 64) sum += w[b * 512 + i] * affine_w[wv * 512 + i];
#pragma unroll
    for (int o = 32; o > 0; o >>= 1) sum += __shfl_down(sum, o);
    if (lane == 0) tdot[wv] = sum;
    if (tid == 0) scnt = 0.f;
    __syncthreads();
    if (tid == 0) {
      const float gain = 0.04419417382415922f;  // 1/sqrt(512)
      float t0 = tdot[0] * gain + affine_b[0];
      float t1 = tdot[1] * gain + affine_b[1];
      float t2 = tdot[2] * gain + affine_b[2];
      float t3 = tdot[3] * gain + affine_b[3];
      float inv = 1.f / sqrtf(t0 * t0 + t1 * t1);
      float c = t0 * inv, s = t1 * inv, tx = t2 * inv, ty = t3 * inv;
      par[0] = c; par[1] = s;
      par[2] = -c * tx + s * ty;   // shift0
      par[3] = -s * tx - c * ty;   // shift1
    }
    __syncthreads();
    const float c = par[0], s = par[1], sh0 = par[2], sh1 = par[3];
    float cnt = 0.f;
    for (int f = tid; f < 1024; f += 256) {
      float fx = freqs[2 * f], fy = freqs[2 * f + 1];
      float fb0 = fx * c + fy * s;
      float fb1 = fy * c - fx * s;
      float ph = phases[f] + fx * sh0 + fy * sh1;
      float nb = sqrtf(fb0 * fb0 + fb1 * fb1);
      float amp = fminf(fmaxf(1.f - (nb - 2.f) * (1.f / 30.f), 0.f), 1.f);
      float4 v; v.x = fb0; v.y = fb1; v.z = ph; v.w = amp;
      freq_data[(b << 10) + f] = v;
      if (sqrtf(fx * fx + fy * fy) < 2.f) cnt += 1.f;
    }
    if (b == 0) {
      atomicAdd(&scnt, cnt);   // integer-valued floats: exact, order-independent
      __syncthreads();
      if (tid == 0) scal[0] = 1.f / sqrtf(scnt);
    }
  } else if (bid < 144) {
    // ---- style: s = fc(w, style_w, style_b); 4 lanes per output ----
    int gt = (bid - 16) * 256 + tid;  // 32768 = 8192 outputs x 4 lanes
    int idx = gt >> 2, part = gt & 3;
    int b = idx >> 9, c = idx & 511;
    const float4* wr = (const float4*)(w + b * 512) + part * 32;
    const float4* sr = (const float4*)(style_w + (size_t)c * 512) + part * 32;
    float sum = 0.f;
#pragma unroll 4
    for (int i = 0; i < 32; ++i) {
      float4 a = wr[i], q = sr[i];
      sum += a.x * q.x + a.y * q.y + a.z * q.z + a.w * q.w;
    }
    sum += __shfl_xor(sum, 1);   // deterministic pairwise tree
    sum += __shfl_xor(sum, 2);
    if (part == 0) s_out[idx] = sum * 0.04419417382415922f + style_b[c];
  } else if (bid < 656) {
    // ---- convw (LDS-stash): normalize -> bt_conv (bf16 [o][kl*512+i]), wsumT[i][o] ----
    const int o = bid - 144;
    __shared__ float cw[4608];
    __shared__ float red[256];
    float sum = 0.f;
    for (int i = tid; i < 4608; i += 256) {
      float v = conv_w[o * 4608 + i];
      cw[i] = v;
      sum += v * v;
    }
    red[tid] = sum;
    __syncthreads();
    for (int off = 128; off > 0; off >>= 1) {
      if (tid < off) red[tid] += red[tid + off];
      __syncthreads();
    }
    const float rn = rsqrtf(red[0] * (1.f / 4608.f));
    for (int i = tid; i < 512; i += 256) {
      float sq = 0.f;
#pragma unroll
      for (int kl = 0; kl < 9; ++kl) {
        float v = cw[i * 9 + kl];   // LDS, stride-9 words: 2-way bank alias only (free)
        sq += v * v;
        bt_conv[o * 4608 + kl * 512 + i] = f2bf(v * rn);
      }
      wsumT[i * 512 + o] = sq * rn * rn;  // transposed for coalesced dcoef reduce
    }
  } else {
    // ---- iw_cast: input_weight f32 -> bf16 (covers 524288 exactly) ----
    int i = (bid - 656) * 256 + tid;
    iw_bf[i] = f2bf(iw[i]);
  }
}

// ---------- GEMM1 (R15): BN=512, single-barrier K-loop; inline inv_rms. ----------
// blocks 0..511: GEMM; 512..639: dcoefs; 640..1159: xmp border zero (disjoint
// from GEMM interior writes; consumed only by next-launch conv). No cross-block
// dependencies within this launch.
__device__ __forceinline__ void sy_sgB(char* lB, const unsigned short* iw, int d,
                                       int rb, int kt, int lane, int lsw) {
  const unsigned short* src = iw + (size_t)(rb + (lane >> 3)) * 1024 + (kt << 6) + lsw;
  gll16(src, lB + d * 65536 + rb * 128);
}

__global__ __launch_bounds__(512, 2) void synth_gemm7_k(
    const float4* __restrict__ freq_data, const unsigned short* __restrict__ iw_bf,
    const float* __restrict__ s_buf, const float* __restrict__ scal,
    const float* __restrict__ wsumT, float* __restrict__ dcoefs,
    unsigned short* __restrict__ xmp) {
  extern __shared__ char sl[];
  const int bid = blockIdx.x;
  const int tid = threadIdx.x, lane = tid & 63, wv = tid >> 6;

  if (bid >= 640) {
    // ---- xmp border zero: 16 b * 260 border px * 64 chunks = 266240 uint4 ----
    int idx = (bid - 640) * 512 + tid;   // 520 blocks x 512
    int chunk = idx & 63;
    int t = idx >> 6;
    int p = t % 260;
    int b = t / 260;
    int h, wq;
    if (p < 66) { h = 0; wq = p; }
    else if (p < 132) { h = 65; wq = p - 66; }
    else if (p < 196) { h = p - 131; wq = 0; }
    else { h = p - 195; wq = 65; }
    uint4 z; z.x = 0; z.y = 0; z.z = 0; z.w = 0;
    *(uint4*)&xmp[(((size_t)b * 66 + h) * 66 + wq) * 512 + chunk * 8] = z;
    return;
  }

  if (bid >= 512) {
    // ---- dcoefs branch: 128 blocks = 16b x 8og ----
    const int bb = (bid - 512) >> 3, og = (bid - 512) & 7;
    float* red = (float*)sl;            // 512 f
    float* sh2 = (float*)(sl + 2048);   // 512 f
    float* red2 = (float*)(sl + 4096);  // 512 f
    float sum = 0.f;
    for (int i = tid; i < 8192; i += 512) { float v = s_buf[i]; sum += v * v; }
    red[tid] = sum;
    __syncthreads();
    for (int off = 256; off > 0; off >>= 1) {
      if (tid < off) red[tid] += red[tid + off];
      __syncthreads();
    }
    const float inv_rms = rsqrtf(red[0] * (1.f / 8192.f));
    {
      float sh = s_buf[bb * 512 + tid] * inv_rms;  // one c per thread
      sh2[tid] = sh * sh;
    }
    __syncthreads();
    const int o = (og << 6) + (tid & 63);
    const int ic = tid >> 6;  // 0..7: i-chunk of 64
    float acc = 0.f;
    for (int i = ic * 64; i < ic * 64 + 64; ++i) acc += wsumT[i * 512 + o] * sh2[i];
    red2[tid] = acc;
    __syncthreads();
    if (tid < 64) {
      float a = 0.f;
#pragma unroll
      for (int k = 0; k < 8; ++k) a += red2[tid + (k << 6)];
      dcoefs[bb * 512 + (og << 6) + tid] = rsqrtf(a + 1e-8f);
    }
    return;
  }

  // ---- GEMM branch ----
  char* lA = sl;            // 2 x (128 rows x 128B), XOR-swizzled sin tile
  char* lB = sl + 32768;    // 2 x (512 rows x 128B), XOR-swizzled via source
  const int wg = (bid & 7) * 64 + (bid >> 3);  // XCD swizzle (512 % 8 == 0)
  const int m0 = wg << 7;
  const int b = m0 >> 12;
  const int hbase = (m0 >> 6) & 63;
  const int wm = (wv >> 2) << 6;        // 2 M-halves of 64 rows
  const int wn = (wv & 3) << 7;         // 4 N-quarters of 128 cols
  const int g = tid & 31;               // freq pair (2 freqs of 64)
  const int r0 = (tid >> 5) << 3;       // 8 rows per thread (of 128)
  const int lsw = (((lane & 7) ^ (lane >> 3)) << 3);
  const int aswz = (((lane >> 4) << 4)) ^ ((lane & 7) << 4);
  const int rowA = (wm + (lane & 15)) * 128;
  const int browB = wn + (lane & 15);
  f32x4 acc[4][8];
#pragma unroll
  for (int mi = 0; mi < 4; ++mi)
#pragma unroll
    for (int ni = 0; ni < 8; ++ni) { f32x4 z = {0.f, 0.f, 0.f, 0.f}; acc[mi][ni] = z; }
  const float gy0 = (hbase + 0.5f) * 0.015625f - 0.5f;
  const float gy1 = (hbase + 1.5f) * 0.015625f - 0.5f;

  // ---- prologue: stage B(0) -> lB[0]; compute sin(0) -> lA[0] ----
#pragma unroll
  for (int ig = 0; ig < 8; ++ig) sy_sgB(lB, iw_bf, 0, wv * 64 + ig * 8, 0, lane, lsw);
  {
    const float4* fdp = freq_data + (b << 10) + (g << 1);
    float4 fd0 = fdp[0], fd1 = fdp[1];
#pragma unroll
    for (int j = 0; j < 8; ++j) {
      const int r = r0 + j;
      const float gx = ((r & 63) + 0.5f) * 0.015625f - 0.5f;
      const float gy = (r >> 6) ? gy1 : gy0;
      ushort2 u;
      u.x = f2bf(sin2pi(gx * fd0.x + gy * fd0.y + fd0.z) * fd0.w);
      u.y = f2bf(sin2pi(gx * fd1.x + gy * fd1.y + fd1.z) * fd1.w);
      *(ushort2*)(lA + r * 128 + ((g << 2) ^ ((r & 7) << 4))) = u;
    }
  }

  for (int kt = 0; kt < 16; ++kt) {
    const int d = kt & 1, dn = d ^ 1;
    // own sin(kt) ds_writes + frag reads drained; B(kt) landed; all-wave rendezvous.
    asm volatile("s_waitcnt lgkmcnt(0)" ::: "memory");
    vmwait<0>();
    __builtin_amdgcn_s_barrier();
    CFENCE();
    __builtin_amdgcn_sched_barrier(0);

    // issue B(kt+1) -> lB[dn] (flies under MFMA + sin)
    if (kt < 15) {
#pragma unroll
      for (int ig = 0; ig < 8; ++ig)
        sy_sgB(lB, iw_bf, dn, wv * 64 + ig * 8, kt + 1, lane, lsw);
    }
    // MFMA(kt): af from lA[d], bq from lB[d]
    const char* pA = lA + d * 16384 + rowA;
    const char* pB = lB + d * 65536 + (size_t)browB * 128;
#pragma unroll
    for (int ks = 0; ks < 2; ++ks) {
      const int ao = aswz ^ (ks << 6);
      bf16x8 af[4], bq[8];
#pragma unroll
      for (int mi = 0; mi < 4; ++mi) af[mi] = *(const bf16x8*)(pA + mi * 2048 + ao);
#pragma unroll
      for (int ni = 0; ni < 8; ++ni) bq[ni] = *(const bf16x8*)(pB + ni * 2048 + ao);
      __builtin_amdgcn_s_setprio(1);
#pragma unroll
      for (int mi = 0; mi < 4; ++mi)
#pragma unroll
        for (int ni = 0; ni < 8; ++ni)
          acc[mi][ni] = __builtin_amdgcn_mfma_f32_16x16x32_bf16(af[mi], bq[ni], acc[mi][ni], 0, 0, 0);
      __builtin_amdgcn_s_setprio(0);
    }
    // sin(kt+1) -> lA[dn] (after this kt's reads; released by next barrier)
    if (kt < 15) {
      const float4* fdp = freq_data + (b << 10) + ((kt + 1) << 6) + (g << 1);
      float4 fd0 = fdp[0], fd1 = fdp[1];
#pragma unroll
      for (int j = 0; j < 8; ++j) {
        const int r = r0 + j;
        const float gx = ((r & 63) + 0.5f) * 0.015625f - 0.5f;
        const float gy = (r >> 6) ? gy1 : gy0;
        ushort2 u;
        u.x = f2bf(sin2pi(gx * fd0.x + gy * fd0.y + fd0.z) * fd0.w);
        u.y = f2bf(sin2pi(gx * fd1.x + gy * fd1.y + fd1.z) * fd1.w);
        *(ushort2*)(lA + dn * 16384 + r * 128 + ((g << 2) ^ ((r & 7) << 4))) = u;
      }
    }
    CFENCE();
  }
  // all waves done reading lA/lB before LDS reuse below
  CFENCE();
  __builtin_amdgcn_s_barrier();
  CFENCE();

  // ---- inline inv_rms over s_buf (deterministic wave-reduce + fixed 8-sum) ----
  float ps = 0.f;
  for (int i = tid; i < 8192; i += 512) { float v = s_buf[i]; ps += v * v; }
#pragma unroll
  for (int o2 = 32; o2 > 0; o2 >>= 1) ps += __shfl_xor(ps, o2);
  float* rsw = (float*)(sl + 163776);   // 8 floats, above lT (ends 133120)
  if (lane == 0) rsw[wv] = ps;
  __syncthreads();
  const float inv_rms = rsqrtf((rsw[0] + rsw[1] + rsw[2] + rsw[3] +
                                rsw[4] + rsw[5] + rsw[6] + rsw[7]) * (1.f / 8192.f));

  // ---- epilogue: LDS transpose (row stride 520 ch = 1040B) -> coalesced stores ----
  const float inv_eff = scal[0];
  const int c_lo = lane & 15, r_hi = (lane >> 4) << 2;
  unsigned short* lT = (unsigned short*)sl;   // 128 x 520 x 2B = 133120 <= 163840
#pragma unroll
  for (int ni = 0; ni < 8; ++ni) {
    const int cc = wn + (ni << 4) + c_lo;
    const float sc = s_buf[b * 512 + cc] * inv_rms * inv_eff;
#pragma unroll
    for (int mi = 0; mi < 4; ++mi) {
#pragma unroll
      for (int j = 0; j < 4; ++j) {
        const int rr = wm + (mi << 4) + r_hi + j;
        lT[rr * 520 + cc] = f2bf(acc[mi][ni][j] * sc);
      }
    }
  }
  asm volatile("s_waitcnt lgkmcnt(0)" ::: "memory");  // own lT writes drained
  __builtin_amdgcn_s_barrier();                       // all waves' lT complete
  CFENCE();
#pragma unroll
  for (int it = 0; it < 16; ++it) {
    const int chunk = it * 512 + tid;   // 8192 chunks x 16B = 128 rows x 1KB
    const int row = chunk >> 6;
    const int co = (chunk & 63) << 3;   // 8 channels per 16B
    uint4 v = *(const uint4*)&lT[row * 520 + co];
    const int hp = hbase + (row >> 6) + 1;
    const int wp = (row & 63) + 1;
    *(uint4*)&xmp[(((size_t)b * 66 + hp) * 66 + wp) * 512 + co] = v;
  }
}

__device__ __forceinline__ float epi_act(float a, float dco, float cb) {
  float y = a * dco + cb;
  y = (y >= 0.f ? y : 0.2f * y) * 1.4142135623730951f;
  return fminf(fmaxf(y, -256.f), 256.f);
}

// ---------- GEMM2: 3x3 conv, 256x256 tile, BK=64, 8 waves (R8-verified) ----------
// kc-major tile order; single-barrier K-tile; all staging 1 tile ahead into D^1.
struct ConvCtx {
  const unsigned short* xmp;
  const unsigned short* bt;
  int n0, hb, b_img, lane;
  int lsw;
  int gB_rb0;
  int gA_lo;
  int gA_up;
};

__device__ __forceinline__ void tile_geom(int t, int& dh, int& dw, int& kc, int& koff) {
  const int kc8 = t / 9;
  const int off = t - 9 * kc8;
  dh = off / 3;
  dw = off - 3 * dh;
  kc = kc8 << 6;
  koff = off * 512 + kc;
}

__device__ __forceinline__ void sgA(char* lds, const ConvCtx& c, int d, int rb,
                                    int dh, int dw, int kc) {
  const int r = rb + (c.lane >> 3);
  const int h = c.hb + (r >> 6) + dh;
  const int w = (r & 63) + dw;
  const unsigned short* src = c.xmp + (((size_t)c.b_img * 66 + h) * 66 + w) * 512 + kc + c.lsw;
  gll16(src, lds + d * 32768 + rb * 128);
}

__device__ __forceinline__ void sgB(char* lds, const ConvCtx& c, int d, int rb, int koff) {
  const int row = c.n0 + rb + (c.lane >> 3);
  const unsigned short* src = c.bt + (size_t)row * 4608 + koff + c.lsw;
  gll16(src, lds + 65536 + d * 32768 + rb * 128);
}

template <bool STG>
__device__ __forceinline__ void conv_tile1(char* lds, const ConvCtx& c, f32x4 (&acc)[8][4],
                                           const char* pA, const char* pB, int aswz0, int t) {
  int dh1, dw1, kc1, koff1;
  tile_geom(t + 1, dh1, dw1, kc1, koff1);
  const int D = t & 1, Dn = D ^ 1;
  const int db = D << 15;
  const int a0 = aswz0, a1 = aswz0 ^ 64;

  vmwait<0>();                       // all stages for tile t (issued during t-1) landed
  __builtin_amdgcn_s_barrier();      // + every wave's stages landed, t-1 reads done
  CFENCE();
  __builtin_amdgcn_sched_barrier(0);

  bf16x8 bq[4], af[4];
  // ---- ks0, mh0 | issue B(t+1) -> D^1 ----
#pragma unroll
  for (int ni = 0; ni < 4; ++ni) bq[ni] = *(const bf16x8*)(pB + db + ni * 2048 + a0);
#pragma unroll
  for (int i = 0; i < 4; ++i) af[i] = *(const bf16x8*)(pA + db + i * 2048 + a0);
  if (STG) {
    sgB(lds, c, Dn, c.gB_rb0, koff1);      sgB(lds, c, Dn, c.gB_rb0 + 8, koff1);
    sgB(lds, c, Dn, c.gB_rb0 + 16, koff1); sgB(lds, c, Dn, c.gB_rb0 + 24, koff1);
  }
  __builtin_amdgcn_s_setprio(1);
#pragma unroll
  for (int i = 0; i < 4; ++i)
#pragma unroll
    for (int ni = 0; ni < 4; ++ni)
      acc[i][ni] = __builtin_amdgcn_mfma_f32_16x16x32_bf16(af[i], bq[ni], acc[i][ni], 0, 0, 0);
  __builtin_amdgcn_s_setprio(0);
  // ---- ks0, mh1 | issue A-up(t+1), A-lo(t+1) -> D^1 ----
#pragma unroll
  for (int i = 0; i < 4; ++i) af[i] = *(const bf16x8*)(pA + db + (4 + i) * 2048 + a0);
  if (STG) {
    sgA(lds, c, Dn, c.gA_up, dh1, dw1, kc1); sgA(lds, c, Dn, c.gA_up + 8, dh1, dw1, kc1);
    sgA(lds, c, Dn, c.gA_lo, dh1, dw1, kc1); sgA(lds, c, Dn, c.gA_lo + 8, dh1, dw1, kc1);
  }
  __builtin_amdgcn_s_setprio(1);
#pragma unroll
  for (int i = 0; i < 4; ++i)
#pragma unroll
    for (int ni = 0; ni < 4; ++ni)
      acc[4 + i][ni] = __builtin_amdgcn_mfma_f32_16x16x32_bf16(af[i], bq[ni], acc[4 + i][ni], 0, 0, 0);
  __builtin_amdgcn_s_setprio(0);
  // ---- ks1, mh0 ----
#pragma unroll
  for (int ni = 0; ni < 4; ++ni) bq[ni] = *(const bf16x8*)(pB + db + ni * 2048 + a1);
#pragma unroll
  for (int i = 0; i < 4; ++i) af[i] = *(const bf16x8*)(pA + db + i * 2048 + a1);
  __builtin_amdgcn_s_setprio(1);
#pragma unroll
  for (int i = 0; i < 4; ++i)
#pragma unroll
    for (int ni = 0; ni < 4; ++ni)
      acc[i][ni] = __builtin_amdgcn_mfma_f32_16x16x32_bf16(af[i], bq[ni], acc[i][ni], 0, 0, 0);
  __builtin_amdgcn_s_setprio(0);
  // ---- ks1, mh1 ----
#pragma unroll
  for (int i = 0; i < 4; ++i) af[i] = *(const bf16x8*)(pA + db + (4 + i) * 2048 + a1);
  __builtin_amdgcn_s_setprio(1);
#pragma unroll
  for (int i = 0; i < 4; ++i)
#pragma unroll
    for (int ni = 0; ni < 4; ++ni)
      acc[4 + i][ni] = __builtin_amdgcn_mfma_f32_16x16x32_bf16(af[i], bq[ni], acc[4 + i][ni], 0, 0, 0);
  __builtin_amdgcn_s_setprio(0);
  CFENCE();
}

__global__ __launch_bounds__(512, 2) void conv_gemm8_k(
    const unsigned short* __restrict__ xmp, const unsigned short* __restrict__ bt_conv,
    const float* __restrict__ dcoefs, const float* __restrict__ conv_b,
    float* __restrict__ out) {
  extern __shared__ char lds[];
  const int tid = threadIdx.x, lane = tid & 63, wv = tid >> 6;
  const int bid = blockIdx.x;
  const int wg = (bid & 7) * 64 + (bid >> 3);  // XCD-bijective swizzle (512 % 8 == 0)
  const int mt = wg >> 1, nt = wg & 1;
  const int m0 = mt << 8, n0 = nt << 8;
  const int b_img = m0 >> 12;
  const int hb = (m0 >> 6) & 63;
  const int wm = (wv >> 2) << 7, wn = (wv & 3) << 6;

  ConvCtx c;
  c.xmp = xmp; c.bt = bt_conv;
  c.n0 = n0; c.hb = hb; c.b_img = b_img; c.lane = lane;
  c.lsw = (((lane & 7) ^ (lane >> 3)) << 3);
  c.gB_rb0 = (((wv & 3) >> 1) << 7) + (((wv & 1) | ((wv >> 2) << 1)) << 5);
  c.gA_lo = wm + ((wv & 3) << 4);
  c.gA_up = c.gA_lo + 64;

  const char* pA = lds + (size_t)(wm + (lane & 15)) * 128;
  const char* pB = lds + 65536 + (size_t)(wn + (lane & 15)) * 128;
  const int aswz0 = (((lane >> 4) << 4)) ^ ((lane & 7) << 4);

  f32x4 acc[8][4];
#pragma unroll
  for (int mi = 0; mi < 8; ++mi)
#pragma unroll
    for (int ni = 0; ni < 4; ++ni) { f32x4 z = {0.f, 0.f, 0.f, 0.f}; acc[mi][ni] = z; }

  // Prologue: stage tile 0 (kc=0, off=0) fully into buf 0. Waited by tile 0's vmcnt(0).
  sgB(lds, c, 0, c.gB_rb0, 0);       sgB(lds, c, 0, c.gB_rb0 + 8, 0);
  sgB(lds, c, 0, c.gB_rb0 + 16, 0);  sgB(lds, c, 0, c.gB_rb0 + 24, 0);
  sgA(lds, c, 0, c.gA_up, 0, 0, 0);  sgA(lds, c, 0, c.gA_up + 8, 0, 0, 0);
  sgA(lds, c, 0, c.gA_lo, 0, 0, 0);  sgA(lds, c, 0, c.gA_lo + 8, 0, 0, 0);

  // 72 K-tiles, kc-major; one barrier + one vmcnt(0) per tile.
  for (int t = 0; t < 71; ++t) conv_tile1<true>(lds, c, acc, pA, pB, aswz0, t);
  conv_tile1<false>(lds, c, acc, pA, pB, aswz0, 71);

  // Epilogue
  const int c_lo = lane & 15, r_hi = (lane >> 4) << 2;
#pragma unroll
  for (int ni = 0; ni < 4; ++ni) {
    const int oo = n0 + wn + (ni << 4) + c_lo;
    const float dco = dcoefs[b_img * 512 + oo];
    const float cb = conv_b[oo];
#pragma unroll
    for (int mi = 0; mi < 8; ++mi) {
      const int rr = wm + (mi << 4) + r_hi;
      const int hh = hb + (rr >> 6);
      const int w0 = rr & 63;
      float4 v;
      v.x = epi_act(acc[mi][ni][0], dco, cb);
      v.y = epi_act(acc[mi][ni][1], dco, cb);
      v.z = epi_act(acc[mi][ni][2], dco, cb);
      v.w = epi_act(acc[mi][ni][3], dco, cb);
      *(float4*)&out[(((size_t)b_img * 512 + oo) * 64 + hh) * 64 + w0] = v;
    }
  }
}

// ---------- launch ----------
extern "C" void kernel_launch(void* const* d_in, const int* in_sizes, int n_in,
                              void* d_out, int out_size, void* d_ws, size_t ws_size,
                              hipStream_t stream) {
  (void)in_sizes; (void)n_in; (void)out_size;
  const float* w        = (const float*)d_in[0];
  const float* affine_w = (const float*)d_in[1];
  const float* affine_b = (const float*)d_in[2];
  const float* freqs    = (const float*)d_in[3];
  const float* phases   = (const float*)d_in[4];
  const float* input_weight = (const float*)d_in[5];
  const float* style_w  = (const float*)d_in[6];
  const float* style_b  = (const float*)d_in[7];
  const float* conv_w   = (const float*)d_in[8];
  const float* conv_b   = (const float*)d_in[9];
  float* out = (float*)d_out;

  char* p = (char*)d_ws;
  float4* freq_data = (float4*)p;               p += (size_t)16 * 1024 * 16;
  float* scal = (float*)p;                      p += 256;
  float* s_buf = (float*)p;                     p += 8192 * 4;
  float* s_hat = (float*)p;                     p += 8192 * 4;   // unused (kept for layout)
  float* wsumT = (float*)p;                     p += (size_t)512 * 512 * 4;
  float* dcoefs = (float*)p;                    p += 8192 * 4;
  unsigned short* iw_bf = (unsigned short*)p;   p += (size_t)512 * 1024 * 2;
  unsigned short* bt_conv = (unsigned short*)p; p += (size_t)512 * 4608 * 2;
  unsigned short* xmp = (unsigned short*)p;     p += (size_t)16 * 66 * 66 * 512 * 2;
  if (ws_size < (size_t)(p - (char*)d_ws)) return;  // workspace too small: fail loudly
  (void)s_hat;

  (void)hipFuncSetAttribute((const void*)conv_gemm8_k,
                            hipFuncAttributeMaxDynamicSharedMemorySize, 131072);
  (void)hipFuncSetAttribute((const void*)synth_gemm7_k,
                            hipFuncAttributeMaxDynamicSharedMemorySize, 163840);

  fused_prep_k<<<2704, 256, 0, stream>>>(w, affine_w, affine_b, freqs, phases,
                                         style_w, style_b, conv_w, input_weight,
                                         freq_data, scal, s_buf, wsumT, bt_conv,
                                         iw_bf);
  synth_gemm7_k<<<1160, 512, 163840, stream>>>(freq_data, iw_bf, s_buf, scal,
                                               wsumT, dcoefs, xmp);
  conv_gemm8_k<<<512, 512, 131072, stream>>>(xmp, bt_conv, dcoefs, conv_b, out);
}